// Round 8
// baseline (312.458 us; speedup 1.0000x reference)
//
#include <hip/hip_runtime.h>
#include <hip/hip_bf16.h>
#include <hip/hip_fp16.h>
#include <math.h>

#define N_NODES 20000
#define E2      240000     // directed edges (2E)
#define EP      120000     // positive edges
#define ENEG    600000     // negative edges
#define ETOT    720000     // EP + ENEG
#define NTILE   11250      // ETOT / 64
#define POSTILE 1875       // EP / 64 (exact: tiles < POSTILE are all-positive)
#define EMLP_BLOCKS 1024   // persistent
#define NCHUNK  20         // scan chunks of 1024

// merged-kernel block ranges
#define WA_B  64
#define W1T_B 256
#define WML_B 128
#define UV_B  2813
#define HA_B  938
#define HP_B  469
#define FA_B  938
#define FP_B  469
#define DIS_B 79

typedef __attribute__((ext_vector_type(8))) short bf16x8;
typedef __attribute__((ext_vector_type(8))) _Float16 f16x8;
typedef __attribute__((ext_vector_type(4))) float f32x4;

__device__ __forceinline__ float logsigf(float x) {
    return fminf(x, 0.0f) - log1pf(expf(-fabsf(x)));
}

__device__ __forceinline__ unsigned short f2bf(float f) {
    unsigned u = __float_as_uint(f);
    u += 0x7FFF + ((u >> 16) & 1);   // RNE
    return (unsigned short)(u >> 16);
}

__device__ __forceinline__ unsigned short f2h(float f) {
    return __half_as_ushort(__float2half(f));
}

__device__ __forceinline__ float bflo(unsigned u) { return __uint_as_float(u << 16); }
__device__ __forceinline__ float bfhi(unsigned u) { return __uint_as_float(u & 0xFFFF0000u); }

__device__ __forceinline__ void store_out(float v, float* p) { *p = v; }
__device__ __forceinline__ void store_out(float v, unsigned short* p) { *p = f2bf(v); }
__device__ __forceinline__ void store_out(float v, __half* p) { *p = __float2half(v); }
__device__ __forceinline__ float load_in(const float* p) { return *p; }
__device__ __forceinline__ float load_in(const unsigned short* p) {
    return __uint_as_float(((unsigned)*p) << 16);
}
__device__ __forceinline__ float load_in(const __half* p) { return __half2float(*p); }

// non-temporal int2 load (uv is read exactly once -> bypass L2 fill so the
// uv stream does not evict the L2-resident h2 table)
__device__ __forceinline__ int2 ldnt_int2(const int2* p) {
    const long long raw = __builtin_nontemporal_load((const long long*)p);
    int2 r; r.x = (int)(unsigned)(raw & 0xFFFFFFFFll); r.y = (int)(raw >> 32);
    return r;
}

union I4H { int4 i; __half2 h[4]; f16x8 f; };

// |a - b| elementwise on 8 packed halves (v_pk_add_f16 w/ neg + v_and)
__device__ __forceinline__ f16x8 make_ad16(int4 a, int4 b) {
    I4H ua, ub, r;
    ua.i = a; ub.i = b;
#pragma unroll
    for (int k = 0; k < 4; ++k) r.h[k] = __habs2(__hsub2(ua.h[k], ub.h[k]));
    return r.f;
}

// a * b elementwise on 8 packed halves (v_pk_mul_f16)
__device__ __forceinline__ f16x8 make_pr16(int4 a, int4 b) {
    I4H ua, ub, r;
    ua.i = a; ub.i = b;
#pragma unroll
    for (int k = 0; k < 4; ++k) r.h[k] = __hmul2(ua.h[k], ub.h[k]);
    return r.f;
}

// --- merged prep: WaT + W1T + WmlT permutes, uv build, both CSR histograms ---
// WaT FRAGMENT-MAJOR layout (fp16, for K9's weight A-fragments):
//   idx = ((nt*8+ks)*64 + lane)*8 + j,  lane = quad*16 + l15
//   maps to logical k' = ks*32 + quad*8 + j of output n = nt*16 + l15, where
//   k' -> orig k: part = k'>>6, d = ((k'>>3)&3)*16 + ((k'>>5)&1)*8 + (k'&7)
// so for lane (quad,l15): frag ks 0/1 -> hu; 2/3 -> hv; 4/5 -> |diff|; 6/7 -> prod
__global__ void k_prep_csr(const float* __restrict__ Wa, unsigned short* __restrict__ WaT,
                           const float* __restrict__ W1, unsigned short* __restrict__ W1T,
                           const float* __restrict__ Wmu, const float* __restrict__ Wlv,
                           unsigned short* __restrict__ WmlT,
                           const int* __restrict__ pos, const int* __restrict__ neg,
                           int2* __restrict__ uv,
                           const int* __restrict__ e_dst, int* __restrict__ cntA,
                           const int* __restrict__ pd, int* __restrict__ cntP) {
    const int b = blockIdx.x, tid = threadIdx.x;
    if (b < WA_B) {
        const int idx = b * 256 + tid;
        const int j    = idx & 7;
        const int lane = (idx >> 3) & 63;
        const int fi   = idx >> 9;           // 0..31
        const int ks = fi & 7, nt = fi >> 3;
        const int quad = lane >> 4, l15 = lane & 15;
        const int n  = nt * 16 + l15;
        const int kp = ks * 32 + quad * 8 + j;
        const int part = kp >> 6;
        const int d = ((kp >> 3) & 3) * 16 + ((kp >> 5) & 1) * 8 + (kp & 7);
        WaT[idx] = f2h(Wa[(part * 64 + d) * 64 + n]);
    } else if (b < WA_B + W1T_B) {
        const int idx = (b - WA_B) * 256 + tid;            // 0..65535
        const int n = idx >> 8, k = idx & 255;
        W1T[idx] = f2bf(W1[k * 256 + n]);
    } else if (b < WA_B + W1T_B + WML_B) {
        const int idx = (b - WA_B - W1T_B) * 256 + tid;    // 0..32767
        const int n = idx >> 8, k = idx & 255;             // n: interleaved col
        const float* W = (n & 1) ? Wlv : Wmu;
        WmlT[idx] = f2bf(W[k * 64 + (n >> 1)]);
    } else if (b < WA_B + W1T_B + WML_B + UV_B) {
        const int j = (b - WA_B - W1T_B - WML_B) * 256 + tid;
        if (j < ETOT) {
            int u, v;
            if (j < EP) { u = pos[j]; v = pos[EP + j]; }
            else        { u = neg[j - EP]; v = neg[ENEG + (j - EP)]; }
            uv[j] = make_int2(u, v);
        }
    } else if (b < WA_B + W1T_B + WML_B + UV_B + HA_B) {
        const int e = (b - WA_B - W1T_B - WML_B - UV_B) * 256 + tid;
        if (e < E2) atomicAdd(&cntA[e_dst[e]], 1);
    } else {
        const int e = (b - WA_B - W1T_B - WML_B - UV_B - HA_B) * 256 + tid;
        if (e < EP) atomicAdd(&cntP[pd[e]], 1);
    }
}

// ---- parallel exclusive scan: 40 blocks (2 arrays x 20 chunks of 1024) ----
__global__ __launch_bounds__(1024) void k_scan_par(const int* __restrict__ cntA,
                                                   int* __restrict__ rsA,
                                                   int* __restrict__ curA,
                                                   const int* __restrict__ cntP,
                                                   int* __restrict__ rsP,
                                                   int* __restrict__ curP) {
    const int arr = blockIdx.x / NCHUNK;
    const int c   = blockIdx.x % NCHUNK;
    const int* cnt = arr ? cntP : cntA;
    int* rs  = arr ? rsP  : rsA;
    int* cur = arr ? curP : curA;
    const int tid = threadIdx.x, lane = tid & 63, wid = tid >> 6;
    __shared__ int wred[16];

    // phase 1: prefix = sum cnt[0 .. c*1024)
    int p = 0;
    for (int i = tid; i < c * 1024; i += 1024) p += cnt[i];
    for (int o = 32; o > 0; o >>= 1) p += __shfl_xor(p, o, 64);
    if (lane == 0) wred[wid] = p;
    __syncthreads();
    int prefix = 0;
#pragma unroll
    for (int k = 0; k < 16; ++k) prefix += wred[k];
    __syncthreads();

    // phase 2: local scan of chunk c
    const int i = c * 1024 + tid;
    const int v = (i < N_NODES) ? cnt[i] : 0;
    int x = v;
#pragma unroll
    for (int d = 1; d < 64; d <<= 1) {
        const int t = __shfl_up(x, d, 64);
        if (lane >= d) x += t;
    }
    if (lane == 63) wred[wid] = x;
    __syncthreads();
    int wexc = 0, tot = 0;
#pragma unroll
    for (int k = 0; k < 16; ++k) { if (k < wid) wexc += wred[k]; tot += wred[k]; }
    const int excl = prefix + wexc + x - v;
    if (i < N_NODES) { rs[i] = excl; cur[i] = excl; }
    if (c == NCHUNK - 1 && tid == 0) rs[N_NODES] = prefix + tot;
}

// ---- merged finish: fill both adjacency lists + dis ----
__global__ void k_finish_csr(const int* __restrict__ e_src, const int* __restrict__ e_dst,
                             int* __restrict__ curA, int* __restrict__ adjA,
                             const int* __restrict__ ps, const int* __restrict__ pd,
                             int* __restrict__ curP, int* __restrict__ adjP,
                             const int* __restrict__ rsP, float* __restrict__ dis) {
    const int b = blockIdx.x, tid = threadIdx.x;
    if (b < FA_B) {
        const int e = b * 256 + tid;
        if (e < E2) {
            const int p = atomicAdd(&curA[e_dst[e]], 1);
            adjA[p] = e_src[e];
        }
    } else if (b < FA_B + FP_B) {
        const int e = (b - FA_B) * 256 + tid;
        if (e < EP) {
            const int p = atomicAdd(&curP[pd[e]], 1);
            adjP[p] = ps[e];
        }
    } else {
        const int i = (b - FA_B - FP_B) * 256 + tid;
        if (i < N_NODES) dis[i] = rsqrtf((float)(rsP[i + 1] - rsP[i] + 1));
    }
}

// ---- K1: m1bf = bf16(x @ W1) via MFMA. grid 625x4: 32-row M x 64-col N ----
__global__ __launch_bounds__(256) void k_mm_xW1_mfma(const float* __restrict__ x,
                                                     const unsigned short* __restrict__ W1T,
                                                     unsigned short* __restrict__ m1) {
    __shared__ unsigned short sA[32 * 264];   // 16896 B
    const int tid = threadIdx.x;
    const int w = tid >> 6, lane = tid & 63;
    const int l15 = lane & 15, quad = lane >> 4;
    const int mb = blockIdx.x >> 2, nb = blockIdx.x & 3;

    // stage A: 32 rows x 256 k, fp32 -> bf16
    for (int i = tid; i < 2048; i += 256) {
        const int row = i >> 6, kc = (i & 63) << 2;
        const float4 xv = *(const float4*)&x[((long)mb * 32 + row) * 256 + kc];
        union { unsigned short s[4]; unsigned long long ll; } pk;
        pk.s[0] = f2bf(xv.x); pk.s[1] = f2bf(xv.y);
        pk.s[2] = f2bf(xv.z); pk.s[3] = f2bf(xv.w);
        *(unsigned long long*)&sA[row * 264 + kc] = pk.ll;
    }

    bf16x8 breg[8];
#pragma unroll
    for (int ks = 0; ks < 8; ++ks)
        breg[ks] = *(const bf16x8*)&W1T[((nb * 64 + w * 16 + l15) << 8) + ks * 32 + quad * 8];
    __syncthreads();

    f32x4 acc[2];
    acc[0] = (f32x4){0.f,0.f,0.f,0.f};
    acc[1] = (f32x4){0.f,0.f,0.f,0.f};
#pragma unroll
    for (int ks = 0; ks < 8; ++ks) {
#pragma unroll
        for (int st = 0; st < 2; ++st) {
            const bf16x8 af = *(const bf16x8*)&sA[(st * 16 + l15) * 264 + ks * 32 + quad * 8];
            acc[st] = __builtin_amdgcn_mfma_f32_16x16x32_bf16(af, breg[ks], acc[st], 0, 0, 0);
        }
    }
    // D: row = quad*4+r (x-row), col = l15 (n)
#pragma unroll
    for (int st = 0; st < 2; ++st)
#pragma unroll
        for (int r = 0; r < 4; ++r)
            m1[((long)mb * 32 + st * 16 + quad * 4 + r) * 256 + nb * 64 + w * 16 + l15] =
                f2bf(acc[st][r]);
}

// ---- K2: h1bf = bf16(relu(LN(segsum(m1bf[adj]) + b1))); 4-way MLP gather ----
__global__ __launch_bounds__(256) void k_gather_ln(const unsigned short* __restrict__ m1,
                                                   const int* __restrict__ rs,
                                                   const int* __restrict__ adj,
                                                   const float* __restrict__ b1,
                                                   const float* __restrict__ g1,
                                                   const float* __restrict__ bt1,
                                                   unsigned short* __restrict__ h1) {
    const int wid = threadIdx.x >> 6, lane = threadIdx.x & 63;
    const int n = blockIdx.x * 4 + wid;
    const int beg = rs[n], end = rs[n + 1];
    float4 a0 = {0.f,0.f,0.f,0.f}, a1 = {0.f,0.f,0.f,0.f};
    float4 a2 = {0.f,0.f,0.f,0.f}, a3 = {0.f,0.f,0.f,0.f};
    int j = beg;
    for (; j + 3 < end; j += 4) {
        const int s0 = adj[j], s1 = adj[j + 1], s2 = adj[j + 2], s3 = adj[j + 3];
        const uint2 u0 = *(const uint2*)(m1 + (long)s0 * 256 + lane * 4);
        const uint2 u1 = *(const uint2*)(m1 + (long)s1 * 256 + lane * 4);
        const uint2 u2 = *(const uint2*)(m1 + (long)s2 * 256 + lane * 4);
        const uint2 u3 = *(const uint2*)(m1 + (long)s3 * 256 + lane * 4);
        a0.x += bflo(u0.x); a0.y += bfhi(u0.x); a0.z += bflo(u0.y); a0.w += bfhi(u0.y);
        a1.x += bflo(u1.x); a1.y += bfhi(u1.x); a1.z += bflo(u1.y); a1.w += bfhi(u1.y);
        a2.x += bflo(u2.x); a2.y += bfhi(u2.x); a2.z += bflo(u2.y); a2.w += bfhi(u2.y);
        a3.x += bflo(u3.x); a3.y += bfhi(u3.x); a3.z += bflo(u3.y); a3.w += bfhi(u3.y);
    }
    for (; j < end; ++j) {
        const int s0 = adj[j];
        const uint2 u = *(const uint2*)(m1 + (long)s0 * 256 + lane * 4);
        a0.x += bflo(u.x); a0.y += bfhi(u.x); a0.z += bflo(u.y); a0.w += bfhi(u.y);
    }
    float4 v;
    const float4 b = *(const float4*)(b1 + lane * 4);
    v.x = (a0.x + a1.x) + (a2.x + a3.x) + b.x;
    v.y = (a0.y + a1.y) + (a2.y + a3.y) + b.y;
    v.z = (a0.z + a1.z) + (a2.z + a3.z) + b.z;
    v.w = (a0.w + a1.w) + (a2.w + a3.w) + b.w;
    float s  = v.x + v.y + v.z + v.w;
    float sq = v.x * v.x + v.y * v.y + v.z * v.z + v.w * v.w;
    for (int o = 32; o > 0; o >>= 1) {
        s  += __shfl_xor(s, o, 64);
        sq += __shfl_xor(sq, o, 64);
    }
    const float mean = s * (1.0f / 256.0f);
    const float var  = sq * (1.0f / 256.0f) - mean * mean;
    const float rsv = rsqrtf(var + 1e-5f);
    const float4 g  = *(const float4*)(g1 + lane * 4);
    const float4 bt = *(const float4*)(bt1 + lane * 4);
    union { unsigned short sh[4]; unsigned long long ll; } pk;
    pk.sh[0] = f2bf(fmaxf((v.x - mean) * rsv * g.x + bt.x, 0.f));
    pk.sh[1] = f2bf(fmaxf((v.y - mean) * rsv * g.y + bt.y, 0.f));
    pk.sh[2] = f2bf(fmaxf((v.z - mean) * rsv * g.z + bt.z, 0.f));
    pk.sh[3] = f2bf(fmaxf((v.w - mean) * rsv * g.w + bt.w, 0.f));
    *(unsigned long long*)&h1[(long)n * 256 + lane * 4] = pk.ll;
}

// ---- K3: hmlbf = bf16(h1bf @ [Wmu|Wlv] interleaved) via MFMA. grid 625x2 ----
__global__ __launch_bounds__(256) void k_mm_hml_mfma(const unsigned short* __restrict__ h1,
                                                     const unsigned short* __restrict__ WmlT,
                                                     unsigned short* __restrict__ hml) {
    __shared__ unsigned short sA[32 * 264];
    const int tid = threadIdx.x;
    const int w = tid >> 6, lane = tid & 63;
    const int l15 = lane & 15, quad = lane >> 4;
    const int mb = blockIdx.x >> 1, nb = blockIdx.x & 1;

    // stage A: 32 rows x 32 chunks of 8 shorts (full 256-k rows)
    for (int i = tid; i < 1024; i += 256) {
        const int row = i >> 5, kc = (i & 31) << 3;
        *(int4*)&sA[row * 264 + kc] = *(const int4*)&h1[((long)mb * 32 + row) * 256 + kc];
    }

    bf16x8 breg[8];
#pragma unroll
    for (int ks = 0; ks < 8; ++ks)
        breg[ks] = *(const bf16x8*)&WmlT[((nb * 64 + w * 16 + l15) << 8) + ks * 32 + quad * 8];
    __syncthreads();

    f32x4 acc[2];
    acc[0] = (f32x4){0.f,0.f,0.f,0.f};
    acc[1] = (f32x4){0.f,0.f,0.f,0.f};
#pragma unroll
    for (int ks = 0; ks < 8; ++ks) {
#pragma unroll
        for (int st = 0; st < 2; ++st) {
            const bf16x8 af = *(const bf16x8*)&sA[(st * 16 + l15) * 264 + ks * 32 + quad * 8];
            acc[st] = __builtin_amdgcn_mfma_f32_16x16x32_bf16(af, breg[ks], acc[st], 0, 0, 0);
        }
    }
#pragma unroll
    for (int st = 0; st < 2; ++st)
#pragma unroll
        for (int r = 0; r < 4; ++r)
            hml[((long)mb * 32 + st * 16 + quad * 4 + r) * 128 + nb * 64 + w * 16 + l15] =
                f2bf(acc[st][r]);
}

// ---- K4: gather hmlbf (interleaved mu/lv) + z (bf16); 4-way MLP gather ----
// kl partial -> per-block array (contended same-address f64 atomics cost ~30us
// in round 4; partial array + k_final is cheaper -- ERRATA round 4).
__global__ __launch_bounds__(256) void k_gather_mulv(const unsigned short* __restrict__ hml,
                                                     const int* __restrict__ rs,
                                                     const int* __restrict__ adj,
                                                     const float* __restrict__ bmu,
                                                     const float* __restrict__ blv,
                                                     const float* __restrict__ eps,
                                                     unsigned short* __restrict__ z,
                                                     double* __restrict__ kl_part) {
    __shared__ double sKL[4];
    const int wid = threadIdx.x >> 6, lane = threadIdx.x & 63;
    const int n = blockIdx.x * 4 + wid;
    const int beg = rs[n], end = rs[n + 1];
    float m0 = 0.f, m1_ = 0.f, m2 = 0.f, m3 = 0.f;
    float l0 = 0.f, l1 = 0.f, l2 = 0.f, l3 = 0.f;
    int j = beg;
    for (; j + 3 < end; j += 4) {
        const int s0 = adj[j], s1 = adj[j + 1], s2 = adj[j + 2], s3 = adj[j + 3];
        const unsigned u0 = *(const unsigned*)(hml + (long)s0 * 128 + lane * 2);
        const unsigned u1 = *(const unsigned*)(hml + (long)s1 * 128 + lane * 2);
        const unsigned u2 = *(const unsigned*)(hml + (long)s2 * 128 + lane * 2);
        const unsigned u3 = *(const unsigned*)(hml + (long)s3 * 128 + lane * 2);
        m0 += bflo(u0); l0 += bfhi(u0);
        m1_ += bflo(u1); l1 += bfhi(u1);
        m2 += bflo(u2); l2 += bfhi(u2);
        m3 += bflo(u3); l3 += bfhi(u3);
    }
    for (; j < end; ++j) {
        const int s0 = adj[j];
        const unsigned u0 = *(const unsigned*)(hml + (long)s0 * 128 + lane * 2);
        m0 += bflo(u0); l0 += bfhi(u0);
    }
    const float mu = (m0 + m1_) + (m2 + m3) + bmu[lane];
    const float lv = (l0 + l1) + (l2 + l3) + blv[lane];
    z[(long)n * 64 + lane] = f2bf(mu + eps[(long)n * 64 + lane] * expf(0.5f * lv));
    float term = 1.0f + lv - mu * mu - expf(lv);
    for (int o = 32; o > 0; o >>= 1) term += __shfl_xor(term, o, 64);
    if (lane == 0) sKL[wid] = (double)term;
    __syncthreads();
    if (threadIdx.x == 0)
        kl_part[blockIdx.x] = sKL[0] + sKL[1] + sKL[2] + sKL[3];
}

// ---- K5/K6: fused decoder layer: 4-way gather_norm + 64x64 matmul + relu ----
template <typename IN, typename OUT>
__global__ __launch_bounds__(256) void k_dec_fused(const IN* __restrict__ feat,
                                                   const int* __restrict__ rs,
                                                   const int* __restrict__ adj,
                                                   const float* __restrict__ dis,
                                                   const float* __restrict__ Wd,
                                                   const float* __restrict__ bd,
                                                   OUT* __restrict__ out) {
    __shared__ float sW[64 * 64];
    __shared__ float rows[4][64];
    const int tid = threadIdx.x;
    {
        const float4* w4 = (const float4*)Wd;
        float4* sw4 = (float4*)sW;
        for (int i = tid; i < 1024; i += 256) sw4[i] = w4[i];
    }
    const int wid = tid >> 6, lane = tid & 63;
    const int n = blockIdx.x * 4 + wid;
    const int beg = rs[n], end = rs[n + 1];
    float a0 = 0.f, a1 = 0.f, a2 = 0.f, a3 = 0.f;
    int j = beg;
    for (; j + 3 < end; j += 4) {
        const int s0 = adj[j], s1 = adj[j + 1], s2 = adj[j + 2], s3 = adj[j + 3];
        a0 += load_in(&feat[(long)s0 * 64 + lane]) * dis[s0];
        a1 += load_in(&feat[(long)s1 * 64 + lane]) * dis[s1];
        a2 += load_in(&feat[(long)s2 * 64 + lane]) * dis[s2];
        a3 += load_in(&feat[(long)s3 * 64 + lane]) * dis[s3];
    }
    for (; j < end; ++j) {
        const int s0 = adj[j];
        a0 += load_in(&feat[(long)s0 * 64 + lane]) * dis[s0];
    }
    const float dn = dis[n];
    rows[wid][lane] = ((a0 + a1) + (a2 + a3)) * dn
                    + load_in(&feat[(long)n * 64 + lane]) * dn * dn;
    __syncthreads();
    float acc = 0.f;
    for (int k = 0; k < 64; k += 4) {
        const float4 a = *(const float4*)&rows[wid][k];
        acc += a.x * sW[(k+0)*64+lane] + a.y * sW[(k+1)*64+lane]
             + a.z * sW[(k+2)*64+lane] + a.w * sW[(k+3)*64+lane];
    }
    store_out(fmaxf(acc + bd[lane], 0.f), &out[(long)n * 64 + lane]);
}

// ---------------- K9: edge MLP, all-register fp16 MFMA, full pipeline --------
// wave = 16 edges x all 64 hidden. B-fragments built entirely in registers:
//   lane (quad,l15): edge = tile*64 + w*16 + l15, owns dims quad*16..quad*16+15
//   frag ks 0/1 -> hu, 2/3 -> hv, 4/5 -> |hu-hv|, 6/7 -> hu*hv (frag-major WaT)
// REGISTER WALL (rounds 2/4/5 ERRATA): any cap <~230 VGPR spills areg. Stay at
// (256,2). Latency schedule:
//  - uv prefetched TWO tiles ahead, non-temporal (full-iteration HBM cover;
//    nt keeps the 2.5MB h2 table L2-resident vs the 5.8MB uv stream)
//  - h2 gathers DOUBLE-BUFFERED: issue t+1's gathers at TOP of iter t into
//    nh* regs (uvB landed a full iteration ago) -> gather latency covered by
//    make_ad/pr + 32 MFMA + epilogue (~4000 cyc), not just the epilogue.
//    (R4 tried this and spilled; R7's LDS ba/Wb freed 32 regs -> now fits:
//    128 areg + 16 acc + 16 h + 16 nh + 4 uv + temps ~= 205 < 256.)
//  - ba/Wb staged in LDS (epilogue reads; frees the 32-reg invariant hoist)
__global__ __launch_bounds__(256, 2) void k_edge_mlp_mfma(
        const __half* __restrict__ h2,
        const int2* __restrict__ uv,
        const unsigned short* __restrict__ WaT,
        const float* __restrict__ ba,
        const float* __restrict__ Wb,
        const float* __restrict__ bb,
        const float* __restrict__ tau,
        double* __restrict__ recon_part) {
    __shared__ float sBa[64], sWb[64];
    __shared__ double sRed[4];
    const int tid = threadIdx.x;
    const int w = tid >> 6, lane = tid & 63;
    const int l15 = lane & 15, quad = lane >> 4;

    if (tid < 64) { sBa[tid] = ba[tid]; sWb[tid] = Wb[tid]; }

    // loop-invariant weight A-fragments (fragment-major layout)
    f16x8 areg[4][8];
#pragma unroll
    for (int nt = 0; nt < 4; ++nt)
#pragma unroll
        for (int ks = 0; ks < 8; ++ks)
            areg[nt][ks] = *(const f16x8*)&WaT[((((nt * 8 + ks) << 6) + lane) << 3)];

    const float bb0 = bb[0];
    const float itau = 1.0f / fmaxf(tau[0], 1e-4f);
    __syncthreads();

    float lsum = 0.f;

    int t = blockIdx.x;
    const int slot = w * 16 + l15;
    // prologue: gathers for tile t; uv one tile ahead
    int2 uvA = ldnt_int2(&uv[t * 64 + slot]);
    int4 hua = *(const int4*)(h2 + (long)uvA.x * 64 + quad * 16);
    int4 hub = *(const int4*)(h2 + (long)uvA.x * 64 + quad * 16 + 8);
    int4 hva = *(const int4*)(h2 + (long)uvA.y * 64 + quad * 16);
    int4 hvb = *(const int4*)(h2 + (long)uvA.y * 64 + quad * 16 + 8);
    int2 uvB = (t + EMLP_BLOCKS < NTILE) ? ldnt_int2(&uv[(t + EMLP_BLOCKS) * 64 + slot]) : uvA;

    for (; t < NTILE; t += EMLP_BLOCKS) {
        // issue uv TWO tiles ahead (nt stream read, full-iteration cover)
        const int t2 = t + 2 * EMLP_BLOCKS;
        const int2 uvC = (t2 < NTILE) ? ldnt_int2(&uv[t2 * 64 + slot]) : uvB;

        // issue NEXT tile's h2 gathers NOW into the dbuf set (uvB landed a
        // full iteration ago) -- whole iteration of cover before consumption
        int4 nhua = hua, nhub = hub, nhva = hva, nhvb = hvb;
        if (t + EMLP_BLOCKS < NTILE) {
            nhua = *(const int4*)(h2 + (long)uvB.x * 64 + quad * 16);
            nhub = *(const int4*)(h2 + (long)uvB.x * 64 + quad * 16 + 8);
            nhva = *(const int4*)(h2 + (long)uvB.y * 64 + quad * 16);
            nhvb = *(const int4*)(h2 + (long)uvB.y * 64 + quad * 16 + 8);
        }

        // derived B-fragments: packed fp16 VALU, register-only
        const f16x8 fad_a = make_ad16(hua, hva);
        const f16x8 fad_b = make_ad16(hub, hvb);
        const f16x8 fpr_a = make_pr16(hua, hva);
        const f16x8 fpr_b = make_pr16(hub, hvb);

        f32x4 acc[4];
#pragma unroll
        for (int nt = 0; nt < 4; ++nt) acc[nt] = (f32x4){0.f, 0.f, 0.f, 0.f};

        const f16x8 bhu_a = *(const f16x8*)&hua;
        const f16x8 bhu_b = *(const f16x8*)&hub;
        const f16x8 bhv_a = *(const f16x8*)&hva;
        const f16x8 bhv_b = *(const f16x8*)&hvb;

#pragma unroll
        for (int nt = 0; nt < 4; ++nt) {
            acc[nt] = __builtin_amdgcn_mfma_f32_16x16x32_f16(areg[nt][0], bhu_a, acc[nt], 0, 0, 0);
            acc[nt] = __builtin_amdgcn_mfma_f32_16x16x32_f16(areg[nt][1], bhu_b, acc[nt], 0, 0, 0);
            acc[nt] = __builtin_amdgcn_mfma_f32_16x16x32_f16(areg[nt][2], bhv_a, acc[nt], 0, 0, 0);
            acc[nt] = __builtin_amdgcn_mfma_f32_16x16x32_f16(areg[nt][3], bhv_b, acc[nt], 0, 0, 0);
            acc[nt] = __builtin_amdgcn_mfma_f32_16x16x32_f16(areg[nt][4], fad_a, acc[nt], 0, 0, 0);
            acc[nt] = __builtin_amdgcn_mfma_f32_16x16x32_f16(areg[nt][5], fad_b, acc[nt], 0, 0, 0);
            acc[nt] = __builtin_amdgcn_mfma_f32_16x16x32_f16(areg[nt][6], fpr_a, acc[nt], 0, 0, 0);
            acc[nt] = __builtin_amdgcn_mfma_f32_16x16x32_f16(areg[nt][7], fpr_b, acc[nt], 0, 0, 0);
        }

        // epilogue: D[n = nt*16 + quad*4 + r][edge = l15]; ba/Wb from LDS
        float s = 0.f;
#pragma unroll
        for (int nt = 0; nt < 4; ++nt) {
            const float4 b4 = *(const float4*)&sBa[nt * 16 + quad * 4];
            const float4 w4 = *(const float4*)&sWb[nt * 16 + quad * 4];
            s += fmaxf(acc[nt][0] + b4.x, 0.f) * w4.x
               + fmaxf(acc[nt][1] + b4.y, 0.f) * w4.y
               + fmaxf(acc[nt][2] + b4.z, 0.f) * w4.z
               + fmaxf(acc[nt][3] + b4.w, 0.f) * w4.w;
        }
        s += __shfl_xor(s, 16, 64);
        s += __shfl_xor(s, 32, 64);
        if (lane < 16) {
            const float logit = (s + bb0) * itau;
            // tiles never mix labels: EP/64 = 1875 exactly (wave-uniform select)
            lsum += (t < POSTILE) ? 5.0f * logsigf(logit) : logsigf(-logit);
        }

        // rotate pipeline registers
        hua = nhua; hub = nhub; hva = nhva; hvb = nhvb;
        uvB = uvC;
    }

    for (int o = 32; o > 0; o >>= 1) lsum += __shfl_xor(lsum, o, 64);
    if (lane == 0) sRed[w] = (double)lsum;
    __syncthreads();
    if (tid == 0)
        recon_part[blockIdx.x] = sRed[0] + sRed[1] + sRed[2] + sRed[3];
}

// ---------------- K10: final reduction over partial arrays ----------------
__global__ __launch_bounds__(1024) void k_final(const double* __restrict__ kl_part,
                                                const double* __restrict__ recon_part,
                                                float* __restrict__ out) {
    __shared__ double sK[16], sR[16];
    const int tid = threadIdx.x, lane = tid & 63, wid = tid >> 6;
    double kl = 0.0, rc = 0.0;
    for (int i = tid; i < 5000; i += 1024) kl += kl_part[i];
    for (int i = tid; i < EMLP_BLOCKS; i += 1024) rc += recon_part[i];
    for (int o = 32; o > 0; o >>= 1) {
        kl += __shfl_xor(kl, o, 64);
        rc += __shfl_xor(rc, o, 64);
    }
    if (lane == 0) { sK[wid] = kl; sR[wid] = rc; }
    __syncthreads();
    if (tid == 0) {
        double K = 0.0, R = 0.0;
        for (int i = 0; i < 16; ++i) { K += sK[i]; R += sR[i]; }
        const double recon = -R / (double)ETOT;
        const double klv = -0.5 * K / ((double)N_NODES * 64.0);
        out[0] = (float)(recon + klv);
        out[1] = (float)recon;
        out[2] = (float)klv;
    }
}

extern "C" void kernel_launch(void* const* d_in, const int* in_sizes, int n_in,
                              void* d_out, int out_size, void* d_ws, size_t ws_size,
                              hipStream_t stream) {
    const float* x   = (const float*)d_in[0];
    const float* eps = (const float*)d_in[1];
    const int* EI    = (const int*)d_in[2];
    const int* pos   = (const int*)d_in[3];
    const int* neg   = (const int*)d_in[4];
    const float* W1  = (const float*)d_in[5];
    const float* b1  = (const float*)d_in[6];
    const float* g1  = (const float*)d_in[7];
    const float* bt1 = (const float*)d_in[8];
    const float* Wmu = (const float*)d_in[9];
    const float* bmu = (const float*)d_in[10];
    const float* Wlv = (const float*)d_in[11];
    const float* blv = (const float*)d_in[12];
    const float* Wd1 = (const float*)d_in[13];
    const float* bd1 = (const float*)d_in[14];
    const float* Wd2 = (const float*)d_in[15];
    const float* bd2 = (const float*)d_in[16];
    const float* Wa  = (const float*)d_in[17];
    const float* ba  = (const float*)d_in[18];
    const float* Wb  = (const float*)d_in[19];
    const float* bb  = (const float*)d_in[20];
    const float* tau = (const float*)d_in[21];

    const int* e_src = EI;
    const int* e_dst = EI + E2;
    const int* ps = pos;
    const int* pd = pos + EP;

    float* ws = (float*)d_ws;
    unsigned short* m1bf  = (unsigned short*)ws;            // [20000,256] bf16 (A)
    unsigned short* hmlbf = (unsigned short*)ws;            // [20000,128] bf16 (A, after m1)
    __half* hdec = (__half*)(ws + 2560000);   // [20000,64] fp16
    __half* h2   = (__half*)(ws + 3840000);   // [20000,64] fp16
    unsigned short* h1bf = (unsigned short*)(ws + 5120000); // [20000,256] bf16 (B)
    unsigned short* z    = (unsigned short*)(ws + 10240000);// [20000,64] bf16
    float* dis   = ws + 11520000;             // [20000]
    unsigned short* WaT = (unsigned short*)(ws + 11540004); // [64,256] fp16 frag-major
    int* cntA = (int*)(ws + 11548200);
    int* rsA  = (int*)(ws + 11568200);
    int* adjA = (int*)(ws + 11588204);
    int* cntP = (int*)(ws + 11828204);
    int* rsP  = (int*)(ws + 11848204);
    int* adjP = (int*)(ws + 11868208);
    int2* uv  = (int2*)(ws + 11988208);       // [720000] int2
    double* kl_part    = (double*)(ws + 13428208); // [5000]
    double* recon_part = (double*)(ws + 13438208); // [1024] -> ends 13440256
    unsigned short* W1T  = (unsigned short*)(ws + 13440256); // [256,256] bf16 -> ends 13473024
    unsigned short* WmlT = (unsigned short*)(ws + 13473024); // [128,256] bf16 -> ends 13489408
    int* curA = (int*)(ws + 13489408);        // [20000] scan cursors (A)
    int* curP = (int*)(ws + 13509408);        // [20000] scan cursors (P)

    hipMemsetAsync(cntA, 0, N_NODES * 4, stream);
    hipMemsetAsync(cntP, 0, N_NODES * 4, stream);

    // prep + CSR (3 launches)
    k_prep_csr<<<WA_B + W1T_B + WML_B + UV_B + HA_B + HP_B, 256, 0, stream>>>(
        Wa, WaT, W1, W1T, Wmu, Wlv, WmlT, pos, neg, uv, e_dst, cntA, pd, cntP);
    k_scan_par<<<2 * NCHUNK, 1024, 0, stream>>>(cntA, rsA, curA, cntP, rsP, curP);
    k_finish_csr<<<FA_B + FP_B + DIS_B, 256, 0, stream>>>(
        e_src, e_dst, curA, adjA, ps, pd, curP, adjP, rsP, dis);

    // encoder (MFMA GEMMs + 4-way gathers)
    k_mm_xW1_mfma<<<2500, 256, 0, stream>>>(x, W1T, m1bf);
    k_gather_ln<<<5000, 256, 0, stream>>>(m1bf, rsA, adjA, b1, g1, bt1, h1bf);
    k_mm_hml_mfma<<<1250, 256, 0, stream>>>(h1bf, WmlT, hmlbf);
    k_gather_mulv<<<5000, 256, 0, stream>>>(hmlbf, rsA, adjA, bmu, blv, eps, z, kl_part);

    // decoder (fp16 intermediates, 4-way gathers)
    k_dec_fused<unsigned short, __half><<<5000, 256, 0, stream>>>(
        z, rsP, adjP, dis, Wd1, bd1, hdec);
    k_dec_fused<__half, __half><<<5000, 256, 0, stream>>>(
        hdec, rsP, adjP, dis, Wd2, bd2, h2);

    // edge MLP + loss
    k_edge_mlp_mfma<<<EMLP_BLOCKS, 256, 0, stream>>>(h2, uv, WaT, ba, Wb, bb, tau, recon_part);
    k_final<<<1, 1024, 0, stream>>>(kl_part, recon_part, (float*)d_out);
}

// Round 9
// 311.858 us; speedup vs baseline: 1.0019x; 1.0019x over previous
//
#include <hip/hip_runtime.h>
#include <hip/hip_bf16.h>
#include <hip/hip_fp16.h>
#include <math.h>

#define N_NODES 20000
#define E2      240000     // directed edges (2E)
#define EP      120000     // positive edges
#define ENEG    600000     // negative edges
#define ETOT    720000     // EP + ENEG
#define NTILE   11250      // ETOT / 64
#define POSTILE 1875       // EP / 64 (exact: tiles < POSTILE are all-positive)
#define EMLP_BLOCKS 512    // persistent, exactly one co-resident pass (2/CU)
#define DEC_BLOCKS 1280    // persistent decoder blocks (grid-stride)
#define NCHUNK  20         // scan chunks of 1024

// merged-kernel block ranges
#define WA_B  64
#define W1T_B 256
#define WML_B 128
#define UV_B  2813
#define HA_B  938
#define HP_B  469
#define FA_B  938
#define FP_B  469
#define DIS_B 79

typedef __attribute__((ext_vector_type(8))) short bf16x8;
typedef __attribute__((ext_vector_type(8))) _Float16 f16x8;
typedef __attribute__((ext_vector_type(4))) float f32x4;

__device__ __forceinline__ float logsigf(float x) {
    return fminf(x, 0.0f) - log1pf(expf(-fabsf(x)));
}

__device__ __forceinline__ unsigned short f2bf(float f) {
    unsigned u = __float_as_uint(f);
    u += 0x7FFF + ((u >> 16) & 1);   // RNE
    return (unsigned short)(u >> 16);
}

__device__ __forceinline__ unsigned short f2h(float f) {
    return __half_as_ushort(__float2half(f));
}

__device__ __forceinline__ float bflo(unsigned u) { return __uint_as_float(u << 16); }
__device__ __forceinline__ float bfhi(unsigned u) { return __uint_as_float(u & 0xFFFF0000u); }

__device__ __forceinline__ void store_out(float v, float* p) { *p = v; }
__device__ __forceinline__ void store_out(float v, unsigned short* p) { *p = f2bf(v); }
__device__ __forceinline__ void store_out(float v, __half* p) { *p = __float2half(v); }
__device__ __forceinline__ float load_in(const float* p) { return *p; }
__device__ __forceinline__ float load_in(const unsigned short* p) {
    return __uint_as_float(((unsigned)*p) << 16);
}
__device__ __forceinline__ float load_in(const __half* p) { return __half2float(*p); }

// non-temporal int2 load (uv is read exactly once -> bypass L2 fill so the
// uv stream does not evict the L2-resident h2 table)
__device__ __forceinline__ int2 ldnt_int2(const int2* p) {
    const long long raw = __builtin_nontemporal_load((const long long*)p);
    int2 r; r.x = (int)(unsigned)(raw & 0xFFFFFFFFll); r.y = (int)(raw >> 32);
    return r;
}

union I4H { int4 i; __half2 h[4]; f16x8 f; };

// |a - b| elementwise on 8 packed halves (v_pk_add_f16 w/ neg + v_and)
__device__ __forceinline__ f16x8 make_ad16(int4 a, int4 b) {
    I4H ua, ub, r;
    ua.i = a; ub.i = b;
#pragma unroll
    for (int k = 0; k < 4; ++k) r.h[k] = __habs2(__hsub2(ua.h[k], ub.h[k]));
    return r.f;
}

// a * b elementwise on 8 packed halves (v_pk_mul_f16)
__device__ __forceinline__ f16x8 make_pr16(int4 a, int4 b) {
    I4H ua, ub, r;
    ua.i = a; ub.i = b;
#pragma unroll
    for (int k = 0; k < 4; ++k) r.h[k] = __hmul2(ua.h[k], ub.h[k]);
    return r.f;
}

// --- merged prep: WaT + W1T + WmlT permutes, uv build, both CSR histograms ---
// WaT FRAGMENT-MAJOR layout (fp16, for K9's weight A-fragments):
//   idx = ((nt*8+ks)*64 + lane)*8 + j,  lane = quad*16 + l15
//   maps to logical k' = ks*32 + quad*8 + j of output n = nt*16 + l15, where
//   k' -> orig k: part = k'>>6, d = ((k'>>3)&3)*16 + ((k'>>5)&1)*8 + (k'&7)
// so for lane (quad,l15): frag ks 0/1 -> hu; 2/3 -> hv; 4/5 -> |diff|; 6/7 -> prod
__global__ void k_prep_csr(const float* __restrict__ Wa, unsigned short* __restrict__ WaT,
                           const float* __restrict__ W1, unsigned short* __restrict__ W1T,
                           const float* __restrict__ Wmu, const float* __restrict__ Wlv,
                           unsigned short* __restrict__ WmlT,
                           const int* __restrict__ pos, const int* __restrict__ neg,
                           int2* __restrict__ uv,
                           const int* __restrict__ e_dst, int* __restrict__ cntA,
                           const int* __restrict__ pd, int* __restrict__ cntP) {
    const int b = blockIdx.x, tid = threadIdx.x;
    if (b < WA_B) {
        const int idx = b * 256 + tid;
        const int j    = idx & 7;
        const int lane = (idx >> 3) & 63;
        const int fi   = idx >> 9;           // 0..31
        const int ks = fi & 7, nt = fi >> 3;
        const int quad = lane >> 4, l15 = lane & 15;
        const int n  = nt * 16 + l15;
        const int kp = ks * 32 + quad * 8 + j;
        const int part = kp >> 6;
        const int d = ((kp >> 3) & 3) * 16 + ((kp >> 5) & 1) * 8 + (kp & 7);
        WaT[idx] = f2h(Wa[(part * 64 + d) * 64 + n]);
    } else if (b < WA_B + W1T_B) {
        const int idx = (b - WA_B) * 256 + tid;            // 0..65535
        const int n = idx >> 8, k = idx & 255;
        W1T[idx] = f2bf(W1[k * 256 + n]);
    } else if (b < WA_B + W1T_B + WML_B) {
        const int idx = (b - WA_B - W1T_B) * 256 + tid;    // 0..32767
        const int n = idx >> 8, k = idx & 255;             // n: interleaved col
        const float* W = (n & 1) ? Wlv : Wmu;
        WmlT[idx] = f2bf(W[k * 64 + (n >> 1)]);
    } else if (b < WA_B + W1T_B + WML_B + UV_B) {
        const int j = (b - WA_B - W1T_B - WML_B) * 256 + tid;
        if (j < ETOT) {
            int u, v;
            if (j < EP) { u = pos[j]; v = pos[EP + j]; }
            else        { u = neg[j - EP]; v = neg[ENEG + (j - EP)]; }
            uv[j] = make_int2(u, v);
        }
    } else if (b < WA_B + W1T_B + WML_B + UV_B + HA_B) {
        const int e = (b - WA_B - W1T_B - WML_B - UV_B) * 256 + tid;
        if (e < E2) atomicAdd(&cntA[e_dst[e]], 1);
    } else {
        const int e = (b - WA_B - W1T_B - WML_B - UV_B - HA_B) * 256 + tid;
        if (e < EP) atomicAdd(&cntP[pd[e]], 1);
    }
}

// ---- parallel exclusive scan: 40 blocks (2 arrays x 20 chunks of 1024) ----
__global__ __launch_bounds__(1024) void k_scan_par(const int* __restrict__ cntA,
                                                   int* __restrict__ rsA,
                                                   int* __restrict__ curA,
                                                   const int* __restrict__ cntP,
                                                   int* __restrict__ rsP,
                                                   int* __restrict__ curP) {
    const int arr = blockIdx.x / NCHUNK;
    const int c   = blockIdx.x % NCHUNK;
    const int* cnt = arr ? cntP : cntA;
    int* rs  = arr ? rsP  : rsA;
    int* cur = arr ? curP : curA;
    const int tid = threadIdx.x, lane = tid & 63, wid = tid >> 6;
    __shared__ int wred[16];

    // phase 1: prefix = sum cnt[0 .. c*1024)
    int p = 0;
    for (int i = tid; i < c * 1024; i += 1024) p += cnt[i];
    for (int o = 32; o > 0; o >>= 1) p += __shfl_xor(p, o, 64);
    if (lane == 0) wred[wid] = p;
    __syncthreads();
    int prefix = 0;
#pragma unroll
    for (int k = 0; k < 16; ++k) prefix += wred[k];
    __syncthreads();

    // phase 2: local scan of chunk c
    const int i = c * 1024 + tid;
    const int v = (i < N_NODES) ? cnt[i] : 0;
    int x = v;
#pragma unroll
    for (int d = 1; d < 64; d <<= 1) {
        const int t = __shfl_up(x, d, 64);
        if (lane >= d) x += t;
    }
    if (lane == 63) wred[wid] = x;
    __syncthreads();
    int wexc = 0, tot = 0;
#pragma unroll
    for (int k = 0; k < 16; ++k) { if (k < wid) wexc += wred[k]; tot += wred[k]; }
    const int excl = prefix + wexc + x - v;
    if (i < N_NODES) { rs[i] = excl; cur[i] = excl; }
    if (c == NCHUNK - 1 && tid == 0) rs[N_NODES] = prefix + tot;
}

// ---- merged finish: fill both adjacency lists + dis ----
__global__ void k_finish_csr(const int* __restrict__ e_src, const int* __restrict__ e_dst,
                             int* __restrict__ curA, int* __restrict__ adjA,
                             const int* __restrict__ ps, const int* __restrict__ pd,
                             int* __restrict__ curP, int* __restrict__ adjP,
                             const int* __restrict__ rsP, float* __restrict__ dis) {
    const int b = blockIdx.x, tid = threadIdx.x;
    if (b < FA_B) {
        const int e = b * 256 + tid;
        if (e < E2) {
            const int p = atomicAdd(&curA[e_dst[e]], 1);
            adjA[p] = e_src[e];
        }
    } else if (b < FA_B + FP_B) {
        const int e = (b - FA_B) * 256 + tid;
        if (e < EP) {
            const int p = atomicAdd(&curP[pd[e]], 1);
            adjP[p] = ps[e];
        }
    } else {
        const int i = (b - FA_B - FP_B) * 256 + tid;
        if (i < N_NODES) dis[i] = rsqrtf((float)(rsP[i + 1] - rsP[i] + 1));
    }
}

// ---- K1: m1bf = bf16(x @ W1) via MFMA. grid 625x4: 32-row M x 64-col N ----
__global__ __launch_bounds__(256) void k_mm_xW1_mfma(const float* __restrict__ x,
                                                     const unsigned short* __restrict__ W1T,
                                                     unsigned short* __restrict__ m1) {
    __shared__ unsigned short sA[32 * 264];   // 16896 B
    const int tid = threadIdx.x;
    const int w = tid >> 6, lane = tid & 63;
    const int l15 = lane & 15, quad = lane >> 4;
    const int mb = blockIdx.x >> 2, nb = blockIdx.x & 3;

    // stage A: 32 rows x 256 k, fp32 -> bf16
    for (int i = tid; i < 2048; i += 256) {
        const int row = i >> 6, kc = (i & 63) << 2;
        const float4 xv = *(const float4*)&x[((long)mb * 32 + row) * 256 + kc];
        union { unsigned short s[4]; unsigned long long ll; } pk;
        pk.s[0] = f2bf(xv.x); pk.s[1] = f2bf(xv.y);
        pk.s[2] = f2bf(xv.z); pk.s[3] = f2bf(xv.w);
        *(unsigned long long*)&sA[row * 264 + kc] = pk.ll;
    }

    bf16x8 breg[8];
#pragma unroll
    for (int ks = 0; ks < 8; ++ks)
        breg[ks] = *(const bf16x8*)&W1T[((nb * 64 + w * 16 + l15) << 8) + ks * 32 + quad * 8];
    __syncthreads();

    f32x4 acc[2];
    acc[0] = (f32x4){0.f,0.f,0.f,0.f};
    acc[1] = (f32x4){0.f,0.f,0.f,0.f};
#pragma unroll
    for (int ks = 0; ks < 8; ++ks) {
#pragma unroll
        for (int st = 0; st < 2; ++st) {
            const bf16x8 af = *(const bf16x8*)&sA[(st * 16 + l15) * 264 + ks * 32 + quad * 8];
            acc[st] = __builtin_amdgcn_mfma_f32_16x16x32_bf16(af, breg[ks], acc[st], 0, 0, 0);
        }
    }
    // D: row = quad*4+r (x-row), col = l15 (n)
#pragma unroll
    for (int st = 0; st < 2; ++st)
#pragma unroll
        for (int r = 0; r < 4; ++r)
            m1[((long)mb * 32 + st * 16 + quad * 4 + r) * 256 + nb * 64 + w * 16 + l15] =
                f2bf(acc[st][r]);
}

// ---- K2: h1bf = bf16(relu(LN(segsum(m1bf[adj]) + b1))); 8-way MLP gather ----
__global__ __launch_bounds__(256) void k_gather_ln(const unsigned short* __restrict__ m1,
                                                   const int* __restrict__ rs,
                                                   const int* __restrict__ adj,
                                                   const float* __restrict__ b1,
                                                   const float* __restrict__ g1,
                                                   const float* __restrict__ bt1,
                                                   unsigned short* __restrict__ h1) {
    const int wid = threadIdx.x >> 6, lane = threadIdx.x & 63;
    const int n = blockIdx.x * 4 + wid;
    const int beg = rs[n], end = rs[n + 1];
    float4 a0 = {0.f,0.f,0.f,0.f}, a1 = {0.f,0.f,0.f,0.f};
    float4 a2 = {0.f,0.f,0.f,0.f}, a3 = {0.f,0.f,0.f,0.f};
    int j = beg;
    for (; j + 7 < end; j += 8) {
        const int s0 = adj[j],     s1 = adj[j + 1], s2 = adj[j + 2], s3 = adj[j + 3];
        const int s4 = adj[j + 4], s5 = adj[j + 5], s6 = adj[j + 6], s7 = adj[j + 7];
        const uint2 u0 = *(const uint2*)(m1 + (long)s0 * 256 + lane * 4);
        const uint2 u1 = *(const uint2*)(m1 + (long)s1 * 256 + lane * 4);
        const uint2 u2 = *(const uint2*)(m1 + (long)s2 * 256 + lane * 4);
        const uint2 u3 = *(const uint2*)(m1 + (long)s3 * 256 + lane * 4);
        const uint2 u4 = *(const uint2*)(m1 + (long)s4 * 256 + lane * 4);
        const uint2 u5 = *(const uint2*)(m1 + (long)s5 * 256 + lane * 4);
        const uint2 u6 = *(const uint2*)(m1 + (long)s6 * 256 + lane * 4);
        const uint2 u7 = *(const uint2*)(m1 + (long)s7 * 256 + lane * 4);
        a0.x += bflo(u0.x); a0.y += bfhi(u0.x); a0.z += bflo(u0.y); a0.w += bfhi(u0.y);
        a1.x += bflo(u1.x); a1.y += bfhi(u1.x); a1.z += bflo(u1.y); a1.w += bfhi(u1.y);
        a2.x += bflo(u2.x); a2.y += bfhi(u2.x); a2.z += bflo(u2.y); a2.w += bfhi(u2.y);
        a3.x += bflo(u3.x); a3.y += bfhi(u3.x); a3.z += bflo(u3.y); a3.w += bfhi(u3.y);
        a0.x += bflo(u4.x); a0.y += bfhi(u4.x); a0.z += bflo(u4.y); a0.w += bfhi(u4.y);
        a1.x += bflo(u5.x); a1.y += bfhi(u5.x); a1.z += bflo(u5.y); a1.w += bfhi(u5.y);
        a2.x += bflo(u6.x); a2.y += bfhi(u6.x); a2.z += bflo(u6.y); a2.w += bfhi(u6.y);
        a3.x += bflo(u7.x); a3.y += bfhi(u7.x); a3.z += bflo(u7.y); a3.w += bfhi(u7.y);
    }
    for (; j + 3 < end; j += 4) {
        const int s0 = adj[j], s1 = adj[j + 1], s2 = adj[j + 2], s3 = adj[j + 3];
        const uint2 u0 = *(const uint2*)(m1 + (long)s0 * 256 + lane * 4);
        const uint2 u1 = *(const uint2*)(m1 + (long)s1 * 256 + lane * 4);
        const uint2 u2 = *(const uint2*)(m1 + (long)s2 * 256 + lane * 4);
        const uint2 u3 = *(const uint2*)(m1 + (long)s3 * 256 + lane * 4);
        a0.x += bflo(u0.x); a0.y += bfhi(u0.x); a0.z += bflo(u0.y); a0.w += bfhi(u0.y);
        a1.x += bflo(u1.x); a1.y += bfhi(u1.x); a1.z += bflo(u1.y); a1.w += bfhi(u1.y);
        a2.x += bflo(u2.x); a2.y += bfhi(u2.x); a2.z += bflo(u2.y); a2.w += bfhi(u2.y);
        a3.x += bflo(u3.x); a3.y += bfhi(u3.x); a3.z += bflo(u3.y); a3.w += bfhi(u3.y);
    }
    for (; j < end; ++j) {
        const int s0 = adj[j];
        const uint2 u = *(const uint2*)(m1 + (long)s0 * 256 + lane * 4);
        a0.x += bflo(u.x); a0.y += bfhi(u.x); a0.z += bflo(u.y); a0.w += bfhi(u.y);
    }
    float4 v;
    const float4 b = *(const float4*)(b1 + lane * 4);
    v.x = (a0.x + a1.x) + (a2.x + a3.x) + b.x;
    v.y = (a0.y + a1.y) + (a2.y + a3.y) + b.y;
    v.z = (a0.z + a1.z) + (a2.z + a3.z) + b.z;
    v.w = (a0.w + a1.w) + (a2.w + a3.w) + b.w;
    float s  = v.x + v.y + v.z + v.w;
    float sq = v.x * v.x + v.y * v.y + v.z * v.z + v.w * v.w;
    for (int o = 32; o > 0; o >>= 1) {
        s  += __shfl_xor(s, o, 64);
        sq += __shfl_xor(sq, o, 64);
    }
    const float mean = s * (1.0f / 256.0f);
    const float var  = sq * (1.0f / 256.0f) - mean * mean;
    const float rsv = rsqrtf(var + 1e-5f);
    const float4 g  = *(const float4*)(g1 + lane * 4);
    const float4 bt = *(const float4*)(bt1 + lane * 4);
    union { unsigned short sh[4]; unsigned long long ll; } pk;
    pk.sh[0] = f2bf(fmaxf((v.x - mean) * rsv * g.x + bt.x, 0.f));
    pk.sh[1] = f2bf(fmaxf((v.y - mean) * rsv * g.y + bt.y, 0.f));
    pk.sh[2] = f2bf(fmaxf((v.z - mean) * rsv * g.z + bt.z, 0.f));
    pk.sh[3] = f2bf(fmaxf((v.w - mean) * rsv * g.w + bt.w, 0.f));
    *(unsigned long long*)&h1[(long)n * 256 + lane * 4] = pk.ll;
}

// ---- K3: hmlbf = bf16(h1bf @ [Wmu|Wlv] interleaved) via MFMA. grid 625x2 ----
__global__ __launch_bounds__(256) void k_mm_hml_mfma(const unsigned short* __restrict__ h1,
                                                     const unsigned short* __restrict__ WmlT,
                                                     unsigned short* __restrict__ hml) {
    __shared__ unsigned short sA[32 * 264];
    const int tid = threadIdx.x;
    const int w = tid >> 6, lane = tid & 63;
    const int l15 = lane & 15, quad = lane >> 4;
    const int mb = blockIdx.x >> 1, nb = blockIdx.x & 1;

    // stage A: 32 rows x 32 chunks of 8 shorts (full 256-k rows)
    for (int i = tid; i < 1024; i += 256) {
        const int row = i >> 5, kc = (i & 31) << 3;
        *(int4*)&sA[row * 264 + kc] = *(const int4*)&h1[((long)mb * 32 + row) * 256 + kc];
    }

    bf16x8 breg[8];
#pragma unroll
    for (int ks = 0; ks < 8; ++ks)
        breg[ks] = *(const bf16x8*)&WmlT[((nb * 64 + w * 16 + l15) << 8) + ks * 32 + quad * 8];
    __syncthreads();

    f32x4 acc[2];
    acc[0] = (f32x4){0.f,0.f,0.f,0.f};
    acc[1] = (f32x4){0.f,0.f,0.f,0.f};
#pragma unroll
    for (int ks = 0; ks < 8; ++ks) {
#pragma unroll
        for (int st = 0; st < 2; ++st) {
            const bf16x8 af = *(const bf16x8*)&sA[(st * 16 + l15) * 264 + ks * 32 + quad * 8];
            acc[st] = __builtin_amdgcn_mfma_f32_16x16x32_bf16(af, breg[ks], acc[st], 0, 0, 0);
        }
    }
#pragma unroll
    for (int st = 0; st < 2; ++st)
#pragma unroll
        for (int r = 0; r < 4; ++r)
            hml[((long)mb * 32 + st * 16 + quad * 4 + r) * 128 + nb * 64 + w * 16 + l15] =
                f2bf(acc[st][r]);
}

// ---- K4: gather hmlbf (interleaved mu/lv) + z (bf16); 8-way MLP gather ----
// kl partial -> per-block array (contended same-address f64 atomics cost ~30us
// in round 4; partial array + k_final is cheaper -- ERRATA round 4).
__global__ __launch_bounds__(256) void k_gather_mulv(const unsigned short* __restrict__ hml,
                                                     const int* __restrict__ rs,
                                                     const int* __restrict__ adj,
                                                     const float* __restrict__ bmu,
                                                     const float* __restrict__ blv,
                                                     const float* __restrict__ eps,
                                                     unsigned short* __restrict__ z,
                                                     double* __restrict__ kl_part) {
    __shared__ double sKL[4];
    const int wid = threadIdx.x >> 6, lane = threadIdx.x & 63;
    const int n = blockIdx.x * 4 + wid;
    const int beg = rs[n], end = rs[n + 1];
    float m0 = 0.f, m1_ = 0.f, m2 = 0.f, m3 = 0.f;
    float l0 = 0.f, l1 = 0.f, l2 = 0.f, l3 = 0.f;
    int j = beg;
    for (; j + 7 < end; j += 8) {
        const int s0 = adj[j],     s1 = adj[j + 1], s2 = adj[j + 2], s3 = adj[j + 3];
        const int s4 = adj[j + 4], s5 = adj[j + 5], s6 = adj[j + 6], s7 = adj[j + 7];
        const unsigned u0 = *(const unsigned*)(hml + (long)s0 * 128 + lane * 2);
        const unsigned u1 = *(const unsigned*)(hml + (long)s1 * 128 + lane * 2);
        const unsigned u2 = *(const unsigned*)(hml + (long)s2 * 128 + lane * 2);
        const unsigned u3 = *(const unsigned*)(hml + (long)s3 * 128 + lane * 2);
        const unsigned u4 = *(const unsigned*)(hml + (long)s4 * 128 + lane * 2);
        const unsigned u5 = *(const unsigned*)(hml + (long)s5 * 128 + lane * 2);
        const unsigned u6 = *(const unsigned*)(hml + (long)s6 * 128 + lane * 2);
        const unsigned u7 = *(const unsigned*)(hml + (long)s7 * 128 + lane * 2);
        m0 += bflo(u0); l0 += bfhi(u0);
        m1_ += bflo(u1); l1 += bfhi(u1);
        m2 += bflo(u2); l2 += bfhi(u2);
        m3 += bflo(u3); l3 += bfhi(u3);
        m0 += bflo(u4); l0 += bfhi(u4);
        m1_ += bflo(u5); l1 += bfhi(u5);
        m2 += bflo(u6); l2 += bfhi(u6);
        m3 += bflo(u7); l3 += bfhi(u7);
    }
    for (; j + 3 < end; j += 4) {
        const int s0 = adj[j], s1 = adj[j + 1], s2 = adj[j + 2], s3 = adj[j + 3];
        const unsigned u0 = *(const unsigned*)(hml + (long)s0 * 128 + lane * 2);
        const unsigned u1 = *(const unsigned*)(hml + (long)s1 * 128 + lane * 2);
        const unsigned u2 = *(const unsigned*)(hml + (long)s2 * 128 + lane * 2);
        const unsigned u3 = *(const unsigned*)(hml + (long)s3 * 128 + lane * 2);
        m0 += bflo(u0); l0 += bfhi(u0);
        m1_ += bflo(u1); l1 += bfhi(u1);
        m2 += bflo(u2); l2 += bfhi(u2);
        m3 += bflo(u3); l3 += bfhi(u3);
    }
    for (; j < end; ++j) {
        const int s0 = adj[j];
        const unsigned u0 = *(const unsigned*)(hml + (long)s0 * 128 + lane * 2);
        m0 += bflo(u0); l0 += bfhi(u0);
    }
    const float mu = (m0 + m1_) + (m2 + m3) + bmu[lane];
    const float lv = (l0 + l1) + (l2 + l3) + blv[lane];
    z[(long)n * 64 + lane] = f2bf(mu + eps[(long)n * 64 + lane] * expf(0.5f * lv));
    float term = 1.0f + lv - mu * mu - expf(lv);
    for (int o = 32; o > 0; o >>= 1) term += __shfl_xor(term, o, 64);
    if (lane == 0) sKL[wid] = (double)term;
    __syncthreads();
    if (threadIdx.x == 0)
        kl_part[blockIdx.x] = sKL[0] + sKL[1] + sKL[2] + sKL[3];
}

// ---- K5/K6: persistent fused decoder layer: gather_norm + 64x64 mm + relu ---
// Grid-stride over 4-node groups: sW (16 KB) staged ONCE per block instead of
// once per 4 nodes (5000x16KB=80MB -> 1280x16KB=20MB L2 traffic per layer).
// rows[] is wave-private (written & read by the same wave) -> no barrier in
// the loop; the single barrier covers sW staging only.
template <typename IN, typename OUT>
__global__ __launch_bounds__(256) void k_dec_fused(const IN* __restrict__ feat,
                                                   const int* __restrict__ rs,
                                                   const int* __restrict__ adj,
                                                   const float* __restrict__ dis,
                                                   const float* __restrict__ Wd,
                                                   const float* __restrict__ bd,
                                                   OUT* __restrict__ out) {
    __shared__ float sW[64 * 64];
    __shared__ float rows[4][64];
    const int tid = threadIdx.x;
    {
        const float4* w4 = (const float4*)Wd;
        float4* sw4 = (float4*)sW;
        for (int i = tid; i < 1024; i += 256) sw4[i] = w4[i];
    }
    const int wid = tid >> 6, lane = tid & 63;
    const float bdl = bd[lane];
    __syncthreads();

    for (int g = blockIdx.x; g < (N_NODES + 3) / 4; g += DEC_BLOCKS) {
        const int n = g * 4 + wid;
        const int beg = rs[n], end = rs[n + 1];
        float a0 = 0.f, a1 = 0.f, a2 = 0.f, a3 = 0.f;
        int j = beg;
        for (; j + 3 < end; j += 4) {
            const int s0 = adj[j], s1 = adj[j + 1], s2 = adj[j + 2], s3 = adj[j + 3];
            a0 += load_in(&feat[(long)s0 * 64 + lane]) * dis[s0];
            a1 += load_in(&feat[(long)s1 * 64 + lane]) * dis[s1];
            a2 += load_in(&feat[(long)s2 * 64 + lane]) * dis[s2];
            a3 += load_in(&feat[(long)s3 * 64 + lane]) * dis[s3];
        }
        for (; j < end; ++j) {
            const int s0 = adj[j];
            a0 += load_in(&feat[(long)s0 * 64 + lane]) * dis[s0];
        }
        const float dn = dis[n];
        rows[wid][lane] = ((a0 + a1) + (a2 + a3)) * dn
                        + load_in(&feat[(long)n * 64 + lane]) * dn * dn;
        // rows[wid] is produced & consumed by wave wid only -> lgkmcnt order
        // within the wave suffices (no __syncthreads).
        float acc = 0.f;
        for (int k = 0; k < 64; k += 4) {
            const float4 a = *(const float4*)&rows[wid][k];
            acc += a.x * sW[(k+0)*64+lane] + a.y * sW[(k+1)*64+lane]
                 + a.z * sW[(k+2)*64+lane] + a.w * sW[(k+3)*64+lane];
        }
        store_out(fmaxf(acc + bdl, 0.f), &out[(long)n * 64 + lane]);
    }
}

// ---------------- K9: edge MLP, all-register fp16 MFMA, full pipeline --------
// wave = 16 edges x all 64 hidden. B-fragments built entirely in registers:
//   lane (quad,l15): edge = tile*64 + w*16 + l15, owns dims quad*16..quad*16+15
//   frag ks 0/1 -> hu, 2/3 -> hv, 4/5 -> |hu-hv|, 6/7 -> hu*hv (frag-major WaT)
// REGISTER WALL (rounds 2/4/5 ERRATA): any cap <~230 VGPR spills areg. Stay at
// (256,2). 512 blocks = exactly one co-resident pass (2/CU x 256 CU): halves
// prologue/drain count vs 1024 (each block runs ~22 iters).
// Latency schedule: uv 2-deep non-temporal prefetch; h2 gathers double-
// buffered (issue t+1 at top of t); ba/Wb staged in LDS.
__global__ __launch_bounds__(256, 2) void k_edge_mlp_mfma(
        const __half* __restrict__ h2,
        const int2* __restrict__ uv,
        const unsigned short* __restrict__ WaT,
        const float* __restrict__ ba,
        const float* __restrict__ Wb,
        const float* __restrict__ bb,
        const float* __restrict__ tau,
        double* __restrict__ recon_part) {
    __shared__ float sBa[64], sWb[64];
    __shared__ double sRed[4];
    const int tid = threadIdx.x;
    const int w = tid >> 6, lane = tid & 63;
    const int l15 = lane & 15, quad = lane >> 4;

    if (tid < 64) { sBa[tid] = ba[tid]; sWb[tid] = Wb[tid]; }

    // loop-invariant weight A-fragments (fragment-major layout)
    f16x8 areg[4][8];
#pragma unroll
    for (int nt = 0; nt < 4; ++nt)
#pragma unroll
        for (int ks = 0; ks < 8; ++ks)
            areg[nt][ks] = *(const f16x8*)&WaT[((((nt * 8 + ks) << 6) + lane) << 3)];

    const float bb0 = bb[0];
    const float itau = 1.0f / fmaxf(tau[0], 1e-4f);
    __syncthreads();

    float lsum = 0.f;

    int t = blockIdx.x;
    const int slot = w * 16 + l15;
    // prologue: gathers for tile t; uv one tile ahead
    int2 uvA = ldnt_int2(&uv[t * 64 + slot]);
    int4 hua = *(const int4*)(h2 + (long)uvA.x * 64 + quad * 16);
    int4 hub = *(const int4*)(h2 + (long)uvA.x * 64 + quad * 16 + 8);
    int4 hva = *(const int4*)(h2 + (long)uvA.y * 64 + quad * 16);
    int4 hvb = *(const int4*)(h2 + (long)uvA.y * 64 + quad * 16 + 8);
    int2 uvB = (t + EMLP_BLOCKS < NTILE) ? ldnt_int2(&uv[(t + EMLP_BLOCKS) * 64 + slot]) : uvA;

    for (; t < NTILE; t += EMLP_BLOCKS) {
        // issue uv TWO tiles ahead (nt stream read, full-iteration cover)
        const int t2 = t + 2 * EMLP_BLOCKS;
        const int2 uvC = (t2 < NTILE) ? ldnt_int2(&uv[t2 * 64 + slot]) : uvB;

        // issue NEXT tile's h2 gathers NOW into the dbuf set (uvB landed a
        // full iteration ago) -- whole iteration of cover before consumption
        int4 nhua = hua, nhub = hub, nhva = hva, nhvb = hvb;
        if (t + EMLP_BLOCKS < NTILE) {
            nhua = *(const int4*)(h2 + (long)uvB.x * 64 + quad * 16);
            nhub = *(const int4*)(h2 + (long)uvB.x * 64 + quad * 16 + 8);
            nhva = *(const int4*)(h2 + (long)uvB.y * 64 + quad * 16);
            nhvb = *(const int4*)(h2 + (long)uvB.y * 64 + quad * 16 + 8);
        }

        // derived B-fragments: packed fp16 VALU, register-only
        const f16x8 fad_a = make_ad16(hua, hva);
        const f16x8 fad_b = make_ad16(hub, hvb);
        const f16x8 fpr_a = make_pr16(hua, hva);
        const f16x8 fpr_b = make_pr16(hub, hvb);

        f32x4 acc[4];
#pragma unroll
        for (int nt = 0; nt < 4; ++nt) acc[nt] = (f32x4){0.f, 0.f, 0.f, 0.f};

        const f16x8 bhu_a = *(const f16x8*)&hua;
        const f16x8 bhu_b = *(const f16x8*)&hub;
        const f16x8 bhv_a = *(const f16x8*)&hva;
        const f16x8 bhv_b = *(const f16x8*)&hvb;

#pragma unroll
        for (int nt = 0; nt < 4; ++nt) {
            acc[nt] = __builtin_amdgcn_mfma_f32_16x16x32_f16(areg[nt][0], bhu_a, acc[nt], 0, 0, 0);
            acc[nt] = __builtin_amdgcn_mfma_f32_16x16x32_f16(areg[nt][1], bhu_b, acc[nt], 0, 0, 0);
            acc[nt] = __builtin_amdgcn_mfma_f32_16x16x32_f16(areg[nt][2], bhv_a, acc[nt], 0, 0, 0);
            acc[nt] = __builtin_amdgcn_mfma_f32_16x16x32_f16(areg[nt][3], bhv_b, acc[nt], 0, 0, 0);
            acc[nt] = __builtin_amdgcn_mfma_f32_16x16x32_f16(areg[nt][4], fad_a, acc[nt], 0, 0, 0);
            acc[nt] = __builtin_amdgcn_mfma_f32_16x16x32_f16(areg[nt][5], fad_b, acc[nt], 0, 0, 0);
            acc[nt] = __builtin_amdgcn_mfma_f32_16x16x32_f16(areg[nt][6], fpr_a, acc[nt], 0, 0, 0);
            acc[nt] = __builtin_amdgcn_mfma_f32_16x16x32_f16(areg[nt][7], fpr_b, acc[nt], 0, 0, 0);
        }

        // epilogue: D[n = nt*16 + quad*4 + r][edge = l15]; ba/Wb from LDS
        float s = 0.f;
#pragma unroll
        for (int nt = 0; nt < 4; ++nt) {
            const float4 b4 = *(const float4*)&sBa[nt * 16 + quad * 4];
            const float4 w4 = *(const float4*)&sWb[nt * 16 + quad * 4];
            s += fmaxf(acc[nt][0] + b4.x, 0.f) * w4.x
               + fmaxf(acc[nt][1] + b4.y, 0.f) * w4.y
               + fmaxf(acc[nt][2] + b4.z, 0.f) * w4.z
               + fmaxf(acc[nt][3] + b4.w, 0.f) * w4.w;
        }
        s += __shfl_xor(s, 16, 64);
        s += __shfl_xor(s, 32, 64);
        if (lane < 16) {
            const float logit = (s + bb0) * itau;
            // tiles never mix labels: EP/64 = 1875 exactly (wave-uniform select)
            lsum += (t < POSTILE) ? 5.0f * logsigf(logit) : logsigf(-logit);
        }

        // rotate pipeline registers
        hua = nhua; hub = nhub; hva = nhva; hvb = nhvb;
        uvB = uvC;
    }

    for (int o = 32; o > 0; o >>= 1) lsum += __shfl_xor(lsum, o, 64);
    if (lane == 0) sRed[w] = (double)lsum;
    __syncthreads();
    if (tid == 0)
        recon_part[blockIdx.x] = sRed[0] + sRed[1] + sRed[2] + sRed[3];
}

// ---------------- K10: final reduction over partial arrays ----------------
__global__ __launch_bounds__(1024) void k_final(const double* __restrict__ kl_part,
                                                const double* __restrict__ recon_part,
                                                float* __restrict__ out) {
    __shared__ double sK[16], sR[16];
    const int tid = threadIdx.x, lane = tid & 63, wid = tid >> 6;
    double kl = 0.0, rc = 0.0;
    for (int i = tid; i < 5000; i += 1024) kl += kl_part[i];
    for (int i = tid; i < EMLP_BLOCKS; i += 1024) rc += recon_part[i];
    for (int o = 32; o > 0; o >>= 1) {
        kl += __shfl_xor(kl, o, 64);
        rc += __shfl_xor(rc, o, 64);
    }
    if (lane == 0) { sK[wid] = kl; sR[wid] = rc; }
    __syncthreads();
    if (tid == 0) {
        double K = 0.0, R = 0.0;
        for (int i = 0; i < 16; ++i) { K += sK[i]; R += sR[i]; }
        const double recon = -R / (double)ETOT;
        const double klv = -0.5 * K / ((double)N_NODES * 64.0);
        out[0] = (float)(recon + klv);
        out[1] = (float)recon;
        out[2] = (float)klv;
    }
}

extern "C" void kernel_launch(void* const* d_in, const int* in_sizes, int n_in,
                              void* d_out, int out_size, void* d_ws, size_t ws_size,
                              hipStream_t stream) {
    const float* x   = (const float*)d_in[0];
    const float* eps = (const float*)d_in[1];
    const int* EI    = (const int*)d_in[2];
    const int* pos   = (const int*)d_in[3];
    const int* neg   = (const int*)d_in[4];
    const float* W1  = (const float*)d_in[5];
    const float* b1  = (const float*)d_in[6];
    const float* g1  = (const float*)d_in[7];
    const float* bt1 = (const float*)d_in[8];
    const float* Wmu = (const float*)d_in[9];
    const float* bmu = (const float*)d_in[10];
    const float* Wlv = (const float*)d_in[11];
    const float* blv = (const float*)d_in[12];
    const float* Wd1 = (const float*)d_in[13];
    const float* bd1 = (const float*)d_in[14];
    const float* Wd2 = (const float*)d_in[15];
    const float* bd2 = (const float*)d_in[16];
    const float* Wa  = (const float*)d_in[17];
    const float* ba  = (const float*)d_in[18];
    const float* Wb  = (const float*)d_in[19];
    const float* bb  = (const float*)d_in[20];
    const float* tau = (const float*)d_in[21];

    const int* e_src = EI;
    const int* e_dst = EI + E2;
    const int* ps = pos;
    const int* pd = pos + EP;

    float* ws = (float*)d_ws;
    unsigned short* m1bf  = (unsigned short*)ws;            // [20000,256] bf16 (A)
    unsigned short* hmlbf = (unsigned short*)ws;            // [20000,128] bf16 (A, after m1)
    __half* hdec = (__half*)(ws + 2560000);   // [20000,64] fp16
    __half* h2   = (__half*)(ws + 3840000);   // [20000,64] fp16
    unsigned short* h1bf = (unsigned short*)(ws + 5120000); // [20000,256] bf16 (B)
    unsigned short* z    = (unsigned short*)(ws + 10240000);// [20000,64] bf16
    float* dis   = ws + 11520000;             // [20000]
    unsigned short* WaT = (unsigned short*)(ws + 11540004); // [64,256] fp16 frag-major
    int* cntA = (int*)(ws + 11548200);
    int* rsA  = (int*)(ws + 11568200);
    int* adjA = (int*)(ws + 11588204);
    int* cntP = (int*)(ws + 11828204);
    int* rsP  = (int*)(ws + 11848204);
    int* adjP = (int*)(ws + 11868208);
    int2* uv  = (int2*)(ws + 11988208);       // [720000] int2
    double* kl_part    = (double*)(ws + 13428208); // [5000]
    double* recon_part = (double*)(ws + 13438208); // [512] -> fits old region
    unsigned short* W1T  = (unsigned short*)(ws + 13440256); // [256,256] bf16 -> ends 13473024
    unsigned short* WmlT = (unsigned short*)(ws + 13473024); // [128,256] bf16 -> ends 13489408
    int* curA = (int*)(ws + 13489408);        // [20000] scan cursors (A)
    int* curP = (int*)(ws + 13509408);        // [20000] scan cursors (P)

    hipMemsetAsync(cntA, 0, N_NODES * 4, stream);
    hipMemsetAsync(cntP, 0, N_NODES * 4, stream);

    // prep + CSR (3 launches)
    k_prep_csr<<<WA_B + W1T_B + WML_B + UV_B + HA_B + HP_B, 256, 0, stream>>>(
        Wa, WaT, W1, W1T, Wmu, Wlv, WmlT, pos, neg, uv, e_dst, cntA, pd, cntP);
    k_scan_par<<<2 * NCHUNK, 1024, 0, stream>>>(cntA, rsA, curA, cntP, rsP, curP);
    k_finish_csr<<<FA_B + FP_B + DIS_B, 256, 0, stream>>>(
        e_src, e_dst, curA, adjA, ps, pd, curP, adjP, rsP, dis);

    // encoder (MFMA GEMMs + 8-way gathers)
    k_mm_xW1_mfma<<<2500, 256, 0, stream>>>(x, W1T, m1bf);
    k_gather_ln<<<5000, 256, 0, stream>>>(m1bf, rsA, adjA, b1, g1, bt1, h1bf);
    k_mm_hml_mfma<<<1250, 256, 0, stream>>>(h1bf, WmlT, hmlbf);
    k_gather_mulv<<<5000, 256, 0, stream>>>(hmlbf, rsA, adjA, bmu, blv, eps, z, kl_part);

    // decoder (persistent grid-stride, fp16 intermediates)
    k_dec_fused<unsigned short, __half><<<DEC_BLOCKS, 256, 0, stream>>>(
        z, rsP, adjP, dis, Wd1, bd1, hdec);
    k_dec_fused<__half, __half><<<DEC_BLOCKS, 256, 0, stream>>>(
        hdec, rsP, adjP, dis, Wd2, bd2, h2);

    // edge MLP + loss
    k_edge_mlp_mfma<<<EMLP_BLOCKS, 256, 0, stream>>>(h2, uv, WaT, ba, Wb, bb, tau, recon_part);
    k_final<<<1, 1024, 0, stream>>>(kl_part, recon_part, (float*)d_out);
}

// Round 11
// 304.415 us; speedup vs baseline: 1.0264x; 1.0245x over previous
//
#include <hip/hip_runtime.h>
#include <hip/hip_bf16.h>
#include <hip/hip_fp16.h>
#include <math.h>

#define N_NODES 20000
#define E2      240000     // directed edges (2E)
#define EP      120000     // positive edges
#define ENEG    600000     // negative edges
#define ETOT    720000     // EP + ENEG
#define NTILE   11250      // ETOT / 64
#define POSTILE 1875       // EP / 64 (exact: tiles < POSTILE are all-positive)
#define EMLP_BLOCKS 512    // persistent, exactly one co-resident pass (2/CU)
#define DEC_BLOCKS 1280    // persistent decoder blocks (grid-stride)
#define NCHUNK  20         // scan chunks of 1024

// merged-kernel block ranges
#define WA_B  64
#define W1T_B 256
#define WML_B 128
#define UV_B  2813
#define HA_B  938
#define HP_B  469
#define FA_B  938
#define FP_B  469

typedef __attribute__((ext_vector_type(8))) short bf16x8;
typedef __attribute__((ext_vector_type(8))) _Float16 f16x8;
typedef __attribute__((ext_vector_type(4))) float f32x4;

__device__ __forceinline__ float logsigf(float x) {
    return fminf(x, 0.0f) - log1pf(expf(-fabsf(x)));
}

__device__ __forceinline__ unsigned short f2bf(float f) {
    unsigned u = __float_as_uint(f);
    u += 0x7FFF + ((u >> 16) & 1);   // RNE
    return (unsigned short)(u >> 16);
}

__device__ __forceinline__ unsigned short f2h(float f) {
    return __half_as_ushort(__float2half(f));
}

__device__ __forceinline__ float bflo(unsigned u) { return __uint_as_float(u << 16); }
__device__ __forceinline__ float bfhi(unsigned u) { return __uint_as_float(u & 0xFFFF0000u); }

__device__ __forceinline__ void store_out(float v, float* p) { *p = v; }
__device__ __forceinline__ void store_out(float v, unsigned short* p) { *p = f2bf(v); }
__device__ __forceinline__ void store_out(float v, __half* p) { *p = __float2half(v); }
__device__ __forceinline__ float load_in(const float* p) { return *p; }
__device__ __forceinline__ float load_in(const unsigned short* p) {
    return __uint_as_float(((unsigned)*p) << 16);
}
__device__ __forceinline__ float load_in(const __half* p) { return __half2float(*p); }

// non-temporal int2 load (uv is read exactly once -> bypass L2 fill so the
// uv stream does not evict the L2-resident h2 table)
__device__ __forceinline__ int2 ldnt_int2(const int2* p) {
    const long long raw = __builtin_nontemporal_load((const long long*)p);
    int2 r; r.x = (int)(unsigned)(raw & 0xFFFFFFFFll); r.y = (int)(raw >> 32);
    return r;
}

union I4H { int4 i; __half2 h[4]; f16x8 f; };

// |a - b| elementwise on 8 packed halves (v_pk_add_f16 w/ neg + v_and)
__device__ __forceinline__ f16x8 make_ad16(int4 a, int4 b) {
    I4H ua, ub, r;
    ua.i = a; ub.i = b;
#pragma unroll
    for (int k = 0; k < 4; ++k) r.h[k] = __habs2(__hsub2(ua.h[k], ub.h[k]));
    return r.f;
}

// a * b elementwise on 8 packed halves (v_pk_mul_f16)
__device__ __forceinline__ f16x8 make_pr16(int4 a, int4 b) {
    I4H ua, ub, r;
    ua.i = a; ub.i = b;
#pragma unroll
    for (int k = 0; k < 4; ++k) r.h[k] = __hmul2(ua.h[k], ub.h[k]);
    return r.f;
}

// --- merged prep: WaT + W1T + WmlT permutes, uv build, both CSR histograms ---
// WaT FRAGMENT-MAJOR layout (fp16, for K9's weight A-fragments):
//   idx = ((nt*8+ks)*64 + lane)*8 + j,  lane = quad*16 + l15
//   maps to logical k' = ks*32 + quad*8 + j of output n = nt*16 + l15, where
//   k' -> orig k: part = k'>>6, d = ((k'>>3)&3)*16 + ((k'>>5)&1)*8 + (k'&7)
// so for lane (quad,l15): frag ks 0/1 -> hu; 2/3 -> hv; 4/5 -> |diff|; 6/7 -> prod
__global__ void k_prep_csr(const float* __restrict__ Wa, unsigned short* __restrict__ WaT,
                           const float* __restrict__ W1, unsigned short* __restrict__ W1T,
                           const float* __restrict__ Wmu, const float* __restrict__ Wlv,
                           unsigned short* __restrict__ WmlT,
                           const int* __restrict__ pos, const int* __restrict__ neg,
                           int2* __restrict__ uv,
                           const int* __restrict__ e_dst, int* __restrict__ cntA,
                           const int* __restrict__ pd, int* __restrict__ cntP) {
    const int b = blockIdx.x, tid = threadIdx.x;
    if (b < WA_B) {
        const int idx = b * 256 + tid;
        const int j    = idx & 7;
        const int lane = (idx >> 3) & 63;
        const int fi   = idx >> 9;           // 0..31
        const int ks = fi & 7, nt = fi >> 3;
        const int quad = lane >> 4, l15 = lane & 15;
        const int n  = nt * 16 + l15;
        const int kp = ks * 32 + quad * 8 + j;
        const int part = kp >> 6;
        const int d = ((kp >> 3) & 3) * 16 + ((kp >> 5) & 1) * 8 + (kp & 7);
        WaT[idx] = f2h(Wa[(part * 64 + d) * 64 + n]);
    } else if (b < WA_B + W1T_B) {
        const int idx = (b - WA_B) * 256 + tid;            // 0..65535
        const int n = idx >> 8, k = idx & 255;
        W1T[idx] = f2bf(W1[k * 256 + n]);
    } else if (b < WA_B + W1T_B + WML_B) {
        const int idx = (b - WA_B - W1T_B) * 256 + tid;    // 0..32767
        const int n = idx >> 8, k = idx & 255;             // n: interleaved col
        const float* W = (n & 1) ? Wlv : Wmu;
        WmlT[idx] = f2bf(W[k * 64 + (n >> 1)]);
    } else if (b < WA_B + W1T_B + WML_B + UV_B) {
        const int j = (b - WA_B - W1T_B - WML_B) * 256 + tid;
        if (j < ETOT) {
            int u, v;
            if (j < EP) { u = pos[j]; v = pos[EP + j]; }
            else        { u = neg[j - EP]; v = neg[ENEG + (j - EP)]; }
            uv[j] = make_int2(u, v);
        }
    } else if (b < WA_B + W1T_B + WML_B + UV_B + HA_B) {
        const int e = (b - WA_B - W1T_B - WML_B - UV_B) * 256 + tid;
        if (e < E2) atomicAdd(&cntA[e_dst[e]], 1);
    } else {
        const int e = (b - WA_B - W1T_B - WML_B - UV_B - HA_B) * 256 + tid;
        if (e < EP) atomicAdd(&cntP[pd[e]], 1);
    }
}

// ---- parallel exclusive scan: 40 blocks (2 arrays x 20 chunks of 1024) ----
// P-array blocks also emit dis[i] = rsqrt(deg+1): rsP[i+1]-rsP[i] == cntP[i],
// so dis needs no separate pass (was the DIS range of k_finish_csr).
__global__ __launch_bounds__(1024) void k_scan_par(const int* __restrict__ cntA,
                                                   int* __restrict__ rsA,
                                                   int* __restrict__ curA,
                                                   const int* __restrict__ cntP,
                                                   int* __restrict__ rsP,
                                                   int* __restrict__ curP,
                                                   float* __restrict__ dis) {
    const int arr = blockIdx.x / NCHUNK;
    const int c   = blockIdx.x % NCHUNK;
    const int* cnt = arr ? cntP : cntA;
    int* rs  = arr ? rsP  : rsA;
    int* cur = arr ? curP : curA;
    const int tid = threadIdx.x, lane = tid & 63, wid = tid >> 6;
    __shared__ int wred[16];

    // phase 1: prefix = sum cnt[0 .. c*1024)
    int p = 0;
    for (int i = tid; i < c * 1024; i += 1024) p += cnt[i];
    for (int o = 32; o > 0; o >>= 1) p += __shfl_xor(p, o, 64);
    if (lane == 0) wred[wid] = p;
    __syncthreads();
    int prefix = 0;
#pragma unroll
    for (int k = 0; k < 16; ++k) prefix += wred[k];
    __syncthreads();

    // phase 2: local scan of chunk c
    const int i = c * 1024 + tid;
    const int v = (i < N_NODES) ? cnt[i] : 0;
    int x = v;
#pragma unroll
    for (int d = 1; d < 64; d <<= 1) {
        const int t = __shfl_up(x, d, 64);
        if (lane >= d) x += t;
    }
    if (lane == 63) wred[wid] = x;
    __syncthreads();
    int wexc = 0, tot = 0;
#pragma unroll
    for (int k = 0; k < 16; ++k) { if (k < wid) wexc += wred[k]; tot += wred[k]; }
    const int excl = prefix + wexc + x - v;
    if (i < N_NODES) {
        rs[i] = excl; cur[i] = excl;
        if (arr) dis[i] = rsqrtf((float)v + 1.0f);
    }
    if (c == NCHUNK - 1 && tid == 0) rs[N_NODES] = prefix + tot;
}

// ---- merged finish: fill both adjacency lists ----
__global__ void k_finish_csr(const int* __restrict__ e_src, const int* __restrict__ e_dst,
                             int* __restrict__ curA, int* __restrict__ adjA,
                             const int* __restrict__ ps, const int* __restrict__ pd,
                             int* __restrict__ curP, int* __restrict__ adjP) {
    const int b = blockIdx.x, tid = threadIdx.x;
    if (b < FA_B) {
        const int e = b * 256 + tid;
        if (e < E2) {
            const int p = atomicAdd(&curA[e_dst[e]], 1);
            adjA[p] = e_src[e];
        }
    } else {
        const int e = (b - FA_B) * 256 + tid;
        if (e < EP) {
            const int p = atomicAdd(&curP[pd[e]], 1);
            adjP[p] = ps[e];
        }
    }
}

// ---- K1: m1bf = bf16(x @ W1) via MFMA. grid 625x4: 32-row M x 64-col N ----
__global__ __launch_bounds__(256) void k_mm_xW1_mfma(const float* __restrict__ x,
                                                     const unsigned short* __restrict__ W1T,
                                                     unsigned short* __restrict__ m1) {
    __shared__ unsigned short sA[32 * 264];   // 16896 B
    const int tid = threadIdx.x;
    const int w = tid >> 6, lane = tid & 63;
    const int l15 = lane & 15, quad = lane >> 4;
    const int mb = blockIdx.x >> 2, nb = blockIdx.x & 3;

    // stage A: 32 rows x 256 k, fp32 -> bf16
    for (int i = tid; i < 2048; i += 256) {
        const int row = i >> 6, kc = (i & 63) << 2;
        const float4 xv = *(const float4*)&x[((long)mb * 32 + row) * 256 + kc];
        union { unsigned short s[4]; unsigned long long ll; } pk;
        pk.s[0] = f2bf(xv.x); pk.s[1] = f2bf(xv.y);
        pk.s[2] = f2bf(xv.z); pk.s[3] = f2bf(xv.w);
        *(unsigned long long*)&sA[row * 264 + kc] = pk.ll;
    }

    bf16x8 breg[8];
#pragma unroll
    for (int ks = 0; ks < 8; ++ks)
        breg[ks] = *(const bf16x8*)&W1T[((nb * 64 + w * 16 + l15) << 8) + ks * 32 + quad * 8];
    __syncthreads();

    f32x4 acc[2];
    acc[0] = (f32x4){0.f,0.f,0.f,0.f};
    acc[1] = (f32x4){0.f,0.f,0.f,0.f};
#pragma unroll
    for (int ks = 0; ks < 8; ++ks) {
#pragma unroll
        for (int st = 0; st < 2; ++st) {
            const bf16x8 af = *(const bf16x8*)&sA[(st * 16 + l15) * 264 + ks * 32 + quad * 8];
            acc[st] = __builtin_amdgcn_mfma_f32_16x16x32_bf16(af, breg[ks], acc[st], 0, 0, 0);
        }
    }
    // D: row = quad*4+r (x-row), col = l15 (n)
#pragma unroll
    for (int st = 0; st < 2; ++st)
#pragma unroll
        for (int r = 0; r < 4; ++r)
            m1[((long)mb * 32 + st * 16 + quad * 4 + r) * 256 + nb * 64 + w * 16 + l15] =
                f2bf(acc[st][r]);
}

// ---- K2: h1bf = bf16(relu(LN(segsum(m1bf[adj]) + b1))); 8-way MLP gather ----
__global__ __launch_bounds__(256) void k_gather_ln(const unsigned short* __restrict__ m1,
                                                   const int* __restrict__ rs,
                                                   const int* __restrict__ adj,
                                                   const float* __restrict__ b1,
                                                   const float* __restrict__ g1,
                                                   const float* __restrict__ bt1,
                                                   unsigned short* __restrict__ h1) {
    const int wid = threadIdx.x >> 6, lane = threadIdx.x & 63;
    const int n = blockIdx.x * 4 + wid;
    const int beg = rs[n], end = rs[n + 1];
    float4 a0 = {0.f,0.f,0.f,0.f}, a1 = {0.f,0.f,0.f,0.f};
    float4 a2 = {0.f,0.f,0.f,0.f}, a3 = {0.f,0.f,0.f,0.f};
    int j = beg;
    for (; j + 7 < end; j += 8) {
        const int s0 = adj[j],     s1 = adj[j + 1], s2 = adj[j + 2], s3 = adj[j + 3];
        const int s4 = adj[j + 4], s5 = adj[j + 5], s6 = adj[j + 6], s7 = adj[j + 7];
        const uint2 u0 = *(const uint2*)(m1 + (long)s0 * 256 + lane * 4);
        const uint2 u1 = *(const uint2*)(m1 + (long)s1 * 256 + lane * 4);
        const uint2 u2 = *(const uint2*)(m1 + (long)s2 * 256 + lane * 4);
        const uint2 u3 = *(const uint2*)(m1 + (long)s3 * 256 + lane * 4);
        const uint2 u4 = *(const uint2*)(m1 + (long)s4 * 256 + lane * 4);
        const uint2 u5 = *(const uint2*)(m1 + (long)s5 * 256 + lane * 4);
        const uint2 u6 = *(const uint2*)(m1 + (long)s6 * 256 + lane * 4);
        const uint2 u7 = *(const uint2*)(m1 + (long)s7 * 256 + lane * 4);
        a0.x += bflo(u0.x); a0.y += bfhi(u0.x); a0.z += bflo(u0.y); a0.w += bfhi(u0.y);
        a1.x += bflo(u1.x); a1.y += bfhi(u1.x); a1.z += bflo(u1.y); a1.w += bfhi(u1.y);
        a2.x += bflo(u2.x); a2.y += bfhi(u2.x); a2.z += bflo(u2.y); a2.w += bfhi(u2.y);
        a3.x += bflo(u3.x); a3.y += bfhi(u3.x); a3.z += bflo(u3.y); a3.w += bfhi(u3.y);
        a0.x += bflo(u4.x); a0.y += bfhi(u4.x); a0.z += bflo(u4.y); a0.w += bfhi(u4.y);
        a1.x += bflo(u5.x); a1.y += bfhi(u5.x); a1.z += bflo(u5.y); a1.w += bfhi(u5.y);
        a2.x += bflo(u6.x); a2.y += bfhi(u6.x); a2.z += bflo(u6.y); a2.w += bfhi(u6.y);
        a3.x += bflo(u7.x); a3.y += bfhi(u7.x); a3.z += bflo(u7.y); a3.w += bfhi(u7.y);
    }
    for (; j + 3 < end; j += 4) {
        const int s0 = adj[j], s1 = adj[j + 1], s2 = adj[j + 2], s3 = adj[j + 3];
        const uint2 u0 = *(const uint2*)(m1 + (long)s0 * 256 + lane * 4);
        const uint2 u1 = *(const uint2*)(m1 + (long)s1 * 256 + lane * 4);
        const uint2 u2 = *(const uint2*)(m1 + (long)s2 * 256 + lane * 4);
        const uint2 u3 = *(const uint2*)(m1 + (long)s3 * 256 + lane * 4);
        a0.x += bflo(u0.x); a0.y += bfhi(u0.x); a0.z += bflo(u0.y); a0.w += bfhi(u0.y);
        a1.x += bflo(u1.x); a1.y += bfhi(u1.x); a1.z += bflo(u1.y); a1.w += bfhi(u1.y);
        a2.x += bflo(u2.x); a2.y += bfhi(u2.x); a2.z += bflo(u2.y); a2.w += bfhi(u2.y);
        a3.x += bflo(u3.x); a3.y += bfhi(u3.x); a3.z += bflo(u3.y); a3.w += bfhi(u3.y);
    }
    for (; j < end; ++j) {
        const int s0 = adj[j];
        const uint2 u = *(const uint2*)(m1 + (long)s0 * 256 + lane * 4);
        a0.x += bflo(u.x); a0.y += bfhi(u.x); a0.z += bflo(u.y); a0.w += bfhi(u.y);
    }
    float4 v;
    const float4 b = *(const float4*)(b1 + lane * 4);
    v.x = (a0.x + a1.x) + (a2.x + a3.x) + b.x;
    v.y = (a0.y + a1.y) + (a2.y + a3.y) + b.y;
    v.z = (a0.z + a1.z) + (a2.z + a3.z) + b.z;
    v.w = (a0.w + a1.w) + (a2.w + a3.w) + b.w;
    float s  = v.x + v.y + v.z + v.w;
    float sq = v.x * v.x + v.y * v.y + v.z * v.z + v.w * v.w;
    for (int o = 32; o > 0; o >>= 1) {
        s  += __shfl_xor(s, o, 64);
        sq += __shfl_xor(sq, o, 64);
    }
    const float mean = s * (1.0f / 256.0f);
    const float var  = sq * (1.0f / 256.0f) - mean * mean;
    const float rsv = rsqrtf(var + 1e-5f);
    const float4 g  = *(const float4*)(g1 + lane * 4);
    const float4 bt = *(const float4*)(bt1 + lane * 4);
    union { unsigned short sh[4]; unsigned long long ll; } pk;
    pk.sh[0] = f2bf(fmaxf((v.x - mean) * rsv * g.x + bt.x, 0.f));
    pk.sh[1] = f2bf(fmaxf((v.y - mean) * rsv * g.y + bt.y, 0.f));
    pk.sh[2] = f2bf(fmaxf((v.z - mean) * rsv * g.z + bt.z, 0.f));
    pk.sh[3] = f2bf(fmaxf((v.w - mean) * rsv * g.w + bt.w, 0.f));
    *(unsigned long long*)&h1[(long)n * 256 + lane * 4] = pk.ll;
}

// ---- K3: hmlbf = bf16(h1bf @ [Wmu|Wlv] interleaved) via MFMA. grid 625x2 ----
__global__ __launch_bounds__(256) void k_mm_hml_mfma(const unsigned short* __restrict__ h1,
                                                     const unsigned short* __restrict__ WmlT,
                                                     unsigned short* __restrict__ hml) {
    __shared__ unsigned short sA[32 * 264];
    const int tid = threadIdx.x;
    const int w = tid >> 6, lane = tid & 63;
    const int l15 = lane & 15, quad = lane >> 4;
    const int mb = blockIdx.x >> 1, nb = blockIdx.x & 1;

    // stage A: 32 rows x 32 chunks of 8 shorts (full 256-k rows)
    for (int i = tid; i < 1024; i += 256) {
        const int row = i >> 5, kc = (i & 31) << 3;
        *(int4*)&sA[row * 264 + kc] = *(const int4*)&h1[((long)mb * 32 + row) * 256 + kc];
    }

    bf16x8 breg[8];
#pragma unroll
    for (int ks = 0; ks < 8; ++ks)
        breg[ks] = *(const bf16x8*)&WmlT[((nb * 64 + w * 16 + l15) << 8) + ks * 32 + quad * 8];
    __syncthreads();

    f32x4 acc[2];
    acc[0] = (f32x4){0.f,0.f,0.f,0.f};
    acc[1] = (f32x4){0.f,0.f,0.f,0.f};
#pragma unroll
    for (int ks = 0; ks < 8; ++ks) {
#pragma unroll
        for (int st = 0; st < 2; ++st) {
            const bf16x8 af = *(const bf16x8*)&sA[(st * 16 + l15) * 264 + ks * 32 + quad * 8];
            acc[st] = __builtin_amdgcn_mfma_f32_16x16x32_bf16(af, breg[ks], acc[st], 0, 0, 0);
        }
    }
#pragma unroll
    for (int st = 0; st < 2; ++st)
#pragma unroll
        for (int r = 0; r < 4; ++r)
            hml[((long)mb * 32 + st * 16 + quad * 4 + r) * 128 + nb * 64 + w * 16 + l15] =
                f2bf(acc[st][r]);
}

// ---- K4: gather hmlbf (interleaved mu/lv) + z (bf16); 8-way MLP gather ----
// kl partial -> per-block array (contended same-address f64 atomics cost ~30us
// in round 4; partial array + k_final is cheaper -- ERRATA round 4).
__global__ __launch_bounds__(256) void k_gather_mulv(const unsigned short* __restrict__ hml,
                                                     const int* __restrict__ rs,
                                                     const int* __restrict__ adj,
                                                     const float* __restrict__ bmu,
                                                     const float* __restrict__ blv,
                                                     const float* __restrict__ eps,
                                                     unsigned short* __restrict__ z,
                                                     double* __restrict__ kl_part) {
    __shared__ double sKL[4];
    const int wid = threadIdx.x >> 6, lane = threadIdx.x & 63;
    const int n = blockIdx.x * 4 + wid;
    const int beg = rs[n], end = rs[n + 1];
    float m0 = 0.f, m1_ = 0.f, m2 = 0.f, m3 = 0.f;
    float l0 = 0.f, l1 = 0.f, l2 = 0.f, l3 = 0.f;
    int j = beg;
    for (; j + 7 < end; j += 8) {
        const int s0 = adj[j],     s1 = adj[j + 1], s2 = adj[j + 2], s3 = adj[j + 3];
        const int s4 = adj[j + 4], s5 = adj[j + 5], s6 = adj[j + 6], s7 = adj[j + 7];
        const unsigned u0 = *(const unsigned*)(hml + (long)s0 * 128 + lane * 2);
        const unsigned u1 = *(const unsigned*)(hml + (long)s1 * 128 + lane * 2);
        const unsigned u2 = *(const unsigned*)(hml + (long)s2 * 128 + lane * 2);
        const unsigned u3 = *(const unsigned*)(hml + (long)s3 * 128 + lane * 2);
        const unsigned u4 = *(const unsigned*)(hml + (long)s4 * 128 + lane * 2);
        const unsigned u5 = *(const unsigned*)(hml + (long)s5 * 128 + lane * 2);
        const unsigned u6 = *(const unsigned*)(hml + (long)s6 * 128 + lane * 2);
        const unsigned u7 = *(const unsigned*)(hml + (long)s7 * 128 + lane * 2);
        m0 += bflo(u0); l0 += bfhi(u0);
        m1_ += bflo(u1); l1 += bfhi(u1);
        m2 += bflo(u2); l2 += bfhi(u2);
        m3 += bflo(u3); l3 += bfhi(u3);
        m0 += bflo(u4); l0 += bfhi(u4);
        m1_ += bflo(u5); l1 += bfhi(u5);
        m2 += bflo(u6); l2 += bfhi(u6);
        m3 += bflo(u7); l3 += bfhi(u7);
    }
    for (; j + 3 < end; j += 4) {
        const int s0 = adj[j], s1 = adj[j + 1], s2 = adj[j + 2], s3 = adj[j + 3];
        const unsigned u0 = *(const unsigned*)(hml + (long)s0 * 128 + lane * 2);
        const unsigned u1 = *(const unsigned*)(hml + (long)s1 * 128 + lane * 2);
        const unsigned u2 = *(const unsigned*)(hml + (long)s2 * 128 + lane * 2);
        const unsigned u3 = *(const unsigned*)(hml + (long)s3 * 128 + lane * 2);
        m0 += bflo(u0); l0 += bfhi(u0);
        m1_ += bflo(u1); l1 += bfhi(u1);
        m2 += bflo(u2); l2 += bfhi(u2);
        m3 += bflo(u3); l3 += bfhi(u3);
    }
    for (; j < end; ++j) {
        const int s0 = adj[j];
        const unsigned u0 = *(const unsigned*)(hml + (long)s0 * 128 + lane * 2);
        m0 += bflo(u0); l0 += bfhi(u0);
    }
    const float mu = (m0 + m1_) + (m2 + m3) + bmu[lane];
    const float lv = (l0 + l1) + (l2 + l3) + blv[lane];
    z[(long)n * 64 + lane] = f2bf(mu + eps[(long)n * 64 + lane] * expf(0.5f * lv));
    float term = 1.0f + lv - mu * mu - expf(lv);
    for (int o = 32; o > 0; o >>= 1) term += __shfl_xor(term, o, 64);
    if (lane == 0) sKL[wid] = (double)term;
    __syncthreads();
    if (threadIdx.x == 0)
        kl_part[blockIdx.x] = sKL[0] + sKL[1] + sKL[2] + sKL[3];
}

// ---- K5/K6: persistent fused decoder layer: gather_norm + 64x64 mm + relu ---
// Grid-stride over 4-node groups: sW (16 KB) staged ONCE per block.
// rows[] is wave-private -> no barrier in the loop.
template <typename IN, typename OUT>
__global__ __launch_bounds__(256) void k_dec_fused(const IN* __restrict__ feat,
                                                   const int* __restrict__ rs,
                                                   const int* __restrict__ adj,
                                                   const float* __restrict__ dis,
                                                   const float* __restrict__ Wd,
                                                   const float* __restrict__ bd,
                                                   OUT* __restrict__ out) {
    __shared__ float sW[64 * 64];
    __shared__ float rows[4][64];
    const int tid = threadIdx.x;
    {
        const float4* w4 = (const float4*)Wd;
        float4* sw4 = (float4*)sW;
        for (int i = tid; i < 1024; i += 256) sw4[i] = w4[i];
    }
    const int wid = tid >> 6, lane = tid & 63;
    const float bdl = bd[lane];
    __syncthreads();

    for (int g = blockIdx.x; g < (N_NODES + 3) / 4; g += DEC_BLOCKS) {
        const int n = g * 4 + wid;
        const int beg = rs[n], end = rs[n + 1];
        float a0 = 0.f, a1 = 0.f, a2 = 0.f, a3 = 0.f;
        int j = beg;
        for (; j + 3 < end; j += 4) {
            const int s0 = adj[j], s1 = adj[j + 1], s2 = adj[j + 2], s3 = adj[j + 3];
            a0 += load_in(&feat[(long)s0 * 64 + lane]) * dis[s0];
            a1 += load_in(&feat[(long)s1 * 64 + lane]) * dis[s1];
            a2 += load_in(&feat[(long)s2 * 64 + lane]) * dis[s2];
            a3 += load_in(&feat[(long)s3 * 64 + lane]) * dis[s3];
        }
        for (; j < end; ++j) {
            const int s0 = adj[j];
            a0 += load_in(&feat[(long)s0 * 64 + lane]) * dis[s0];
        }
        const float dn = dis[n];
        rows[wid][lane] = ((a0 + a1) + (a2 + a3)) * dn
                        + load_in(&feat[(long)n * 64 + lane]) * dn * dn;
        float acc = 0.f;
        for (int k = 0; k < 64; k += 4) {
            const float4 a = *(const float4*)&rows[wid][k];
            acc += a.x * sW[(k+0)*64+lane] + a.y * sW[(k+1)*64+lane]
                 + a.z * sW[(k+2)*64+lane] + a.w * sW[(k+3)*64+lane];
        }
        store_out(fmaxf(acc + bdl, 0.f), &out[(long)n * 64 + lane]);
    }
}

// ---------------- K9: edge MLP, all-register fp16 MFMA, full pipeline --------
// wave = 16 edges x all 64 hidden. B-fragments built entirely in registers:
//   lane (quad,l15): edge = tile*64 + w*16 + l15, owns dims quad*16..quad*16+15
//   frag ks 0/1 -> hu, 2/3 -> hv, 4/5 -> |hu-hv|, 6/7 -> hu*hv (frag-major WaT)
// REGISTER WALL (rounds 2/4/5 ERRATA): any cap <~230 VGPR spills areg. Stay at
// (256,2). 512 blocks = exactly one co-resident pass (2/CU x 256 CU).
// Latency: uv 2-deep nt prefetch; h2 gathers double-buffered; ba/Wb in LDS.
// (Round-10 ERRATA: fused tail + cross-block counter removed -- the bench
// container failed twice with it in; separate k_final is the measured-good
// configuration and the fusion was worth only ~1 launch boundary.)
__global__ __launch_bounds__(256, 2) void k_edge_mlp_mfma(
        const __half* __restrict__ h2,
        const int2* __restrict__ uv,
        const unsigned short* __restrict__ WaT,
        const float* __restrict__ ba,
        const float* __restrict__ Wb,
        const float* __restrict__ bb,
        const float* __restrict__ tau,
        double* __restrict__ recon_part) {
    __shared__ float sBa[64], sWb[64];
    __shared__ double sRed[4];
    const int tid = threadIdx.x;
    const int w = tid >> 6, lane = tid & 63;
    const int l15 = lane & 15, quad = lane >> 4;

    if (tid < 64) { sBa[tid] = ba[tid]; sWb[tid] = Wb[tid]; }

    // loop-invariant weight A-fragments (fragment-major layout)
    f16x8 areg[4][8];
#pragma unroll
    for (int nt = 0; nt < 4; ++nt)
#pragma unroll
        for (int ks = 0; ks < 8; ++ks)
            areg[nt][ks] = *(const f16x8*)&WaT[((((nt * 8 + ks) << 6) + lane) << 3)];

    const float bb0 = bb[0];
    const float itau = 1.0f / fmaxf(tau[0], 1e-4f);
    __syncthreads();

    float lsum = 0.f;

    int t = blockIdx.x;
    const int slot = w * 16 + l15;
    // prologue: gathers for tile t; uv one tile ahead
    int2 uvA = ldnt_int2(&uv[t * 64 + slot]);
    int4 hua = *(const int4*)(h2 + (long)uvA.x * 64 + quad * 16);
    int4 hub = *(const int4*)(h2 + (long)uvA.x * 64 + quad * 16 + 8);
    int4 hva = *(const int4*)(h2 + (long)uvA.y * 64 + quad * 16);
    int4 hvb = *(const int4*)(h2 + (long)uvA.y * 64 + quad * 16 + 8);
    int2 uvB = (t + EMLP_BLOCKS < NTILE) ? ldnt_int2(&uv[(t + EMLP_BLOCKS) * 64 + slot]) : uvA;

    for (; t < NTILE; t += EMLP_BLOCKS) {
        // issue uv TWO tiles ahead (nt stream read, full-iteration cover)
        const int t2 = t + 2 * EMLP_BLOCKS;
        const int2 uvC = (t2 < NTILE) ? ldnt_int2(&uv[t2 * 64 + slot]) : uvB;

        // issue NEXT tile's h2 gathers NOW into the dbuf set (uvB landed a
        // full iteration ago) -- whole iteration of cover before consumption
        int4 nhua = hua, nhub = hub, nhva = hva, nhvb = hvb;
        if (t + EMLP_BLOCKS < NTILE) {
            nhua = *(const int4*)(h2 + (long)uvB.x * 64 + quad * 16);
            nhub = *(const int4*)(h2 + (long)uvB.x * 64 + quad * 16 + 8);
            nhva = *(const int4*)(h2 + (long)uvB.y * 64 + quad * 16);
            nhvb = *(const int4*)(h2 + (long)uvB.y * 64 + quad * 16 + 8);
        }

        // derived B-fragments: packed fp16 VALU, register-only
        const f16x8 fad_a = make_ad16(hua, hva);
        const f16x8 fad_b = make_ad16(hub, hvb);
        const f16x8 fpr_a = make_pr16(hua, hva);
        const f16x8 fpr_b = make_pr16(hub, hvb);

        f32x4 acc[4];
#pragma unroll
        for (int nt = 0; nt < 4; ++nt) acc[nt] = (f32x4){0.f, 0.f, 0.f, 0.f};

        const f16x8 bhu_a = *(const f16x8*)&hua;
        const f16x8 bhu_b = *(const f16x8*)&hub;
        const f16x8 bhv_a = *(const f16x8*)&hva;
        const f16x8 bhv_b = *(const f16x8*)&hvb;

#pragma unroll
        for (int nt = 0; nt < 4; ++nt) {
            acc[nt] = __builtin_amdgcn_mfma_f32_16x16x32_f16(areg[nt][0], bhu_a, acc[nt], 0, 0, 0);
            acc[nt] = __builtin_amdgcn_mfma_f32_16x16x32_f16(areg[nt][1], bhu_b, acc[nt], 0, 0, 0);
            acc[nt] = __builtin_amdgcn_mfma_f32_16x16x32_f16(areg[nt][2], bhv_a, acc[nt], 0, 0, 0);
            acc[nt] = __builtin_amdgcn_mfma_f32_16x16x32_f16(areg[nt][3], bhv_b, acc[nt], 0, 0, 0);
            acc[nt] = __builtin_amdgcn_mfma_f32_16x16x32_f16(areg[nt][4], fad_a, acc[nt], 0, 0, 0);
            acc[nt] = __builtin_amdgcn_mfma_f32_16x16x32_f16(areg[nt][5], fad_b, acc[nt], 0, 0, 0);
            acc[nt] = __builtin_amdgcn_mfma_f32_16x16x32_f16(areg[nt][6], fpr_a, acc[nt], 0, 0, 0);
            acc[nt] = __builtin_amdgcn_mfma_f32_16x16x32_f16(areg[nt][7], fpr_b, acc[nt], 0, 0, 0);
        }

        // epilogue: D[n = nt*16 + quad*4 + r][edge = l15]; ba/Wb from LDS
        float s = 0.f;
#pragma unroll
        for (int nt = 0; nt < 4; ++nt) {
            const float4 b4 = *(const float4*)&sBa[nt * 16 + quad * 4];
            const float4 w4 = *(const float4*)&sWb[nt * 16 + quad * 4];
            s += fmaxf(acc[nt][0] + b4.x, 0.f) * w4.x
               + fmaxf(acc[nt][1] + b4.y, 0.f) * w4.y
               + fmaxf(acc[nt][2] + b4.z, 0.f) * w4.z
               + fmaxf(acc[nt][3] + b4.w, 0.f) * w4.w;
        }
        s += __shfl_xor(s, 16, 64);
        s += __shfl_xor(s, 32, 64);
        if (lane < 16) {
            const float logit = (s + bb0) * itau;
            // tiles never mix labels: EP/64 = 1875 exactly (wave-uniform select)
            lsum += (t < POSTILE) ? 5.0f * logsigf(logit) : logsigf(-logit);
        }

        // rotate pipeline registers
        hua = nhua; hub = nhub; hva = nhva; hvb = nhvb;
        uvB = uvC;
    }

    for (int o = 32; o > 0; o >>= 1) lsum += __shfl_xor(lsum, o, 64);
    if (lane == 0) sRed[w] = (double)lsum;
    __syncthreads();
    if (tid == 0)
        recon_part[blockIdx.x] = sRed[0] + sRed[1] + sRed[2] + sRed[3];
}

// ---------------- K10: final reduction over partial arrays ----------------
__global__ __launch_bounds__(1024) void k_final(const double* __restrict__ kl_part,
                                                const double* __restrict__ recon_part,
                                                float* __restrict__ out) {
    __shared__ double sK[16], sR[16];
    const int tid = threadIdx.x, lane = tid & 63, wid = tid >> 6;
    double kl = 0.0, rc = 0.0;
    for (int i = tid; i < 5000; i += 1024) kl += kl_part[i];
    for (int i = tid; i < EMLP_BLOCKS; i += 1024) rc += recon_part[i];
    for (int o = 32; o > 0; o >>= 1) {
        kl += __shfl_xor(kl, o, 64);
        rc += __shfl_xor(rc, o, 64);
    }
    if (lane == 0) { sK[wid] = kl; sR[wid] = rc; }
    __syncthreads();
    if (tid == 0) {
        double K = 0.0, R = 0.0;
        for (int i = 0; i < 16; ++i) { K += sK[i]; R += sR[i]; }
        const double recon = -R / (double)ETOT;
        const double klv = -0.5 * K / ((double)N_NODES * 64.0);
        out[0] = (float)(recon + klv);
        out[1] = (float)recon;
        out[2] = (float)klv;
    }
}

extern "C" void kernel_launch(void* const* d_in, const int* in_sizes, int n_in,
                              void* d_out, int out_size, void* d_ws, size_t ws_size,
                              hipStream_t stream) {
    const float* x   = (const float*)d_in[0];
    const float* eps = (const float*)d_in[1];
    const int* EI    = (const int*)d_in[2];
    const int* pos   = (const int*)d_in[3];
    const int* neg   = (const int*)d_in[4];
    const float* W1  = (const float*)d_in[5];
    const float* b1  = (const float*)d_in[6];
    const float* g1  = (const float*)d_in[7];
    const float* bt1 = (const float*)d_in[8];
    const float* Wmu = (const float*)d_in[9];
    const float* bmu = (const float*)d_in[10];
    const float* Wlv = (const float*)d_in[11];
    const float* blv = (const float*)d_in[12];
    const float* Wd1 = (const float*)d_in[13];
    const float* bd1 = (const float*)d_in[14];
    const float* Wd2 = (const float*)d_in[15];
    const float* bd2 = (const float*)d_in[16];
    const float* Wa  = (const float*)d_in[17];
    const float* ba  = (const float*)d_in[18];
    const float* Wb  = (const float*)d_in[19];
    const float* bb  = (const float*)d_in[20];
    const float* tau = (const float*)d_in[21];

    const int* e_src = EI;
    const int* e_dst = EI + E2;
    const int* ps = pos;
    const int* pd = pos + EP;

    float* ws = (float*)d_ws;
    unsigned short* m1bf  = (unsigned short*)ws;            // [20000,256] bf16 (A)
    unsigned short* hmlbf = (unsigned short*)ws;            // [20000,128] bf16 (A, after m1)
    __half* hdec = (__half*)(ws + 2560000);   // [20000,64] fp16
    __half* h2   = (__half*)(ws + 3840000);   // [20000,64] fp16
    unsigned short* h1bf = (unsigned short*)(ws + 5120000); // [20000,256] bf16 (B)
    unsigned short* z    = (unsigned short*)(ws + 10240000);// [20000,64] bf16
    float* dis   = ws + 11520000;             // [20000]
    unsigned short* WaT = (unsigned short*)(ws + 11540004); // [64,256] fp16 frag-major
    int* cntA = (int*)(ws + 11548200);        // [20000]  (cntP adjacent: 1 memset)
    int* cntP = (int*)(ws + 11568200);        // [20000]
    int* rsA  = (int*)(ws + 11588200);        // [20001]
    int* adjA = (int*)(ws + 11608204);        // [240000]
    int* rsP  = (int*)(ws + 11848204);        // [20001]
    int* adjP = (int*)(ws + 11868208);        // [120000]
    int2* uv  = (int2*)(ws + 11988208);       // [720000] int2 -> ends 13428208
    double* kl_part    = (double*)(ws + 13428208); // [5000]  -> ends 13438208
    double* recon_part = (double*)(ws + 13438208); // [512]
    unsigned short* W1T  = (unsigned short*)(ws + 13440256); // [256,256] bf16
    unsigned short* WmlT = (unsigned short*)(ws + 13473024); // [128,256] bf16
    int* curA = (int*)(ws + 13489408);        // [20000] scan cursors (A)
    int* curP = (int*)(ws + 13509408);        // [20000] scan cursors (P)

    hipMemsetAsync(cntA, 0, 2 * N_NODES * 4, stream);   // cntA+cntP, one call

    // prep + CSR (3 launches)
    k_prep_csr<<<WA_B + W1T_B + WML_B + UV_B + HA_B + HP_B, 256, 0, stream>>>(
        Wa, WaT, W1, W1T, Wmu, Wlv, WmlT, pos, neg, uv, e_dst, cntA, pd, cntP);
    k_scan_par<<<2 * NCHUNK, 1024, 0, stream>>>(cntA, rsA, curA, cntP, rsP, curP, dis);
    k_finish_csr<<<FA_B + FP_B, 256, 0, stream>>>(
        e_src, e_dst, curA, adjA, ps, pd, curP, adjP);

    // encoder (MFMA GEMMs + 8-way gathers)
    k_mm_xW1_mfma<<<2500, 256, 0, stream>>>(x, W1T, m1bf);
    k_gather_ln<<<5000, 256, 0, stream>>>(m1bf, rsA, adjA, b1, g1, bt1, h1bf);
    k_mm_hml_mfma<<<1250, 256, 0, stream>>>(h1bf, WmlT, hmlbf);
    k_gather_mulv<<<5000, 256, 0, stream>>>(hmlbf, rsA, adjA, bmu, blv, eps, z, kl_part);

    // decoder (persistent grid-stride, fp16 intermediates)
    k_dec_fused<unsigned short, __half><<<DEC_BLOCKS, 256, 0, stream>>>(
        z, rsP, adjP, dis, Wd1, bd1, hdec);
    k_dec_fused<__half, __half><<<DEC_BLOCKS, 256, 0, stream>>>(
        hdec, rsP, adjP, dis, Wd2, bd2, h2);

    // edge MLP + loss
    k_edge_mlp_mfma<<<EMLP_BLOCKS, 256, 0, stream>>>(h2, uv, WaT, ba, Wb, bb, tau, recon_part);
    k_final<<<1, 1024, 0, stream>>>(kl_part, recon_part, (float*)d_out);
}

// Round 12
// 298.440 us; speedup vs baseline: 1.0470x; 1.0200x over previous
//
#include <hip/hip_runtime.h>
#include <hip/hip_bf16.h>
#include <hip/hip_fp16.h>
#include <math.h>

#define N_NODES 20000
#define E2      240000     // directed edges (2E)
#define EP      120000     // positive edges
#define ENEG    600000     // negative edges
#define ETOT    720000     // EP + ENEG
#define NTILE   11250      // ETOT / 64
#define POSTILE 1875       // EP / 64 (exact: tiles < POSTILE are all-positive)
#define EMLP_BLOCKS 512    // persistent, exactly one co-resident pass (2/CU)
#define DEC_BLOCKS 1280    // persistent decoder blocks (grid-stride)
#define NCHUNK  20         // scan chunks of 1024

// merged-kernel block ranges (prep)
#define WA_B  64
#define W1T_B 256
#define WML_B 128
#define UV_B  2813
#define HA_B  938
#define HP_B  469
// merged finish+mm ranges: scatter blocks FIRST (dispatch early, latency-bound),
// MFMA blocks behind them fill the machine.
#define FA_B  938
#define FP_B  469
#define FMM_SCATTER (FA_B + FP_B)   // 1407
#define FMM_MM 2500                 // mm_xW1 blocks

typedef __attribute__((ext_vector_type(8))) short bf16x8;
typedef __attribute__((ext_vector_type(8))) _Float16 f16x8;
typedef __attribute__((ext_vector_type(4))) float f32x4;

__device__ __forceinline__ float logsigf(float x) {
    return fminf(x, 0.0f) - log1pf(expf(-fabsf(x)));
}

__device__ __forceinline__ unsigned short f2bf(float f) {
    unsigned u = __float_as_uint(f);
    u += 0x7FFF + ((u >> 16) & 1);   // RNE
    return (unsigned short)(u >> 16);
}

__device__ __forceinline__ unsigned short f2h(float f) {
    return __half_as_ushort(__float2half(f));
}

__device__ __forceinline__ float bflo(unsigned u) { return __uint_as_float(u << 16); }
__device__ __forceinline__ float bfhi(unsigned u) { return __uint_as_float(u & 0xFFFF0000u); }

__device__ __forceinline__ void store_out(float v, float* p) { *p = v; }
__device__ __forceinline__ void store_out(float v, unsigned short* p) { *p = f2bf(v); }
__device__ __forceinline__ void store_out(float v, __half* p) { *p = __float2half(v); }
__device__ __forceinline__ float load_in(const float* p) { return *p; }
__device__ __forceinline__ float load_in(const unsigned short* p) {
    return __uint_as_float(((unsigned)*p) << 16);
}
__device__ __forceinline__ float load_in(const __half* p) { return __half2float(*p); }

// non-temporal int2 load (uv is read exactly once -> bypass L2 fill so the
// uv stream does not evict the L2-resident h2 table)
__device__ __forceinline__ int2 ldnt_int2(const int2* p) {
    const long long raw = __builtin_nontemporal_load((const long long*)p);
    int2 r; r.x = (int)(unsigned)(raw & 0xFFFFFFFFll); r.y = (int)(raw >> 32);
    return r;
}
__device__ __forceinline__ void stnt_int2(int2* p, int2 v) {
    const long long raw = ((long long)(unsigned)v.y << 32) | (unsigned)v.x;
    __builtin_nontemporal_store(raw, (long long*)p);
}

union I4H { int4 i; __half2 h[4]; f16x8 f; };

// |a - b| elementwise on 8 packed halves (v_pk_add_f16 w/ neg + v_and)
__device__ __forceinline__ f16x8 make_ad16(int4 a, int4 b) {
    I4H ua, ub, r;
    ua.i = a; ub.i = b;
#pragma unroll
    for (int k = 0; k < 4; ++k) r.h[k] = __habs2(__hsub2(ua.h[k], ub.h[k]));
    return r.f;
}

// a * b elementwise on 8 packed halves (v_pk_mul_f16)
__device__ __forceinline__ f16x8 make_pr16(int4 a, int4 b) {
    I4H ua, ub, r;
    ua.i = a; ub.i = b;
#pragma unroll
    for (int k = 0; k < 4; ++k) r.h[k] = __hmul2(ua.h[k], ub.h[k]);
    return r.f;
}

// --- merged prep: WaT + W1T + WmlT permutes, uv build, both CSR histograms ---
// WaT FRAGMENT-MAJOR layout (fp16, for K9's weight A-fragments):
//   idx = ((nt*8+ks)*64 + lane)*8 + j,  lane = quad*16 + l15
//   maps to logical k' = ks*32 + quad*8 + j of output n = nt*16 + l15, where
//   k' -> orig k: part = k'>>6, d = ((k'>>3)&3)*16 + ((k'>>5)&1)*8 + (k'&7)
// so for lane (quad,l15): frag ks 0/1 -> hu; 2/3 -> hv; 4/5 -> |diff|; 6/7 -> prod
__global__ void k_prep_csr(const float* __restrict__ Wa, unsigned short* __restrict__ WaT,
                           const float* __restrict__ W1, unsigned short* __restrict__ W1T,
                           const float* __restrict__ Wmu, const float* __restrict__ Wlv,
                           unsigned short* __restrict__ WmlT,
                           const int* __restrict__ pos, const int* __restrict__ neg,
                           int2* __restrict__ uv,
                           const int* __restrict__ e_dst, int* __restrict__ cntA,
                           const int* __restrict__ pd, int* __restrict__ cntP) {
    const int b = blockIdx.x, tid = threadIdx.x;
    if (b < WA_B) {
        const int idx = b * 256 + tid;
        const int j    = idx & 7;
        const int lane = (idx >> 3) & 63;
        const int fi   = idx >> 9;           // 0..31
        const int ks = fi & 7, nt = fi >> 3;
        const int quad = lane >> 4, l15 = lane & 15;
        const int n  = nt * 16 + l15;
        const int kp = ks * 32 + quad * 8 + j;
        const int part = kp >> 6;
        const int d = ((kp >> 3) & 3) * 16 + ((kp >> 5) & 1) * 8 + (kp & 7);
        WaT[idx] = f2h(Wa[(part * 64 + d) * 64 + n]);
    } else if (b < WA_B + W1T_B) {
        const int idx = (b - WA_B) * 256 + tid;            // 0..65535
        const int n = idx >> 8, k = idx & 255;
        W1T[idx] = f2bf(W1[k * 256 + n]);
    } else if (b < WA_B + W1T_B + WML_B) {
        const int idx = (b - WA_B - W1T_B) * 256 + tid;    // 0..32767
        const int n = idx >> 8, k = idx & 255;             // n: interleaved col
        const float* W = (n & 1) ? Wlv : Wmu;
        WmlT[idx] = f2bf(W[k * 64 + (n >> 1)]);
    } else if (b < WA_B + W1T_B + WML_B + UV_B) {
        const int j = (b - WA_B - W1T_B - WML_B) * 256 + tid;
        if (j < ETOT) {
            int u, v;
            if (j < EP) { u = pos[j]; v = pos[EP + j]; }
            else        { u = neg[j - EP]; v = neg[ENEG + (j - EP)]; }
            stnt_int2(&uv[j], make_int2(u, v));   // written once, read once (nt)
        }
    } else if (b < WA_B + W1T_B + WML_B + UV_B + HA_B) {
        const int e = (b - WA_B - W1T_B - WML_B - UV_B) * 256 + tid;
        if (e < E2) atomicAdd(&cntA[e_dst[e]], 1);
    } else {
        const int e = (b - WA_B - W1T_B - WML_B - UV_B - HA_B) * 256 + tid;
        if (e < EP) atomicAdd(&cntP[pd[e]], 1);
    }
}

// ---- parallel exclusive scan: 40 blocks (2 arrays x 20 chunks of 1024) ----
// P-array blocks also emit dis[i] = rsqrt(deg+1): rsP[i+1]-rsP[i] == cntP[i],
// so dis needs no separate pass.
__global__ __launch_bounds__(1024) void k_scan_par(const int* __restrict__ cntA,
                                                   int* __restrict__ rsA,
                                                   int* __restrict__ curA,
                                                   const int* __restrict__ cntP,
                                                   int* __restrict__ rsP,
                                                   int* __restrict__ curP,
                                                   float* __restrict__ dis) {
    const int arr = blockIdx.x / NCHUNK;
    const int c   = blockIdx.x % NCHUNK;
    const int* cnt = arr ? cntP : cntA;
    int* rs  = arr ? rsP  : rsA;
    int* cur = arr ? curP : curA;
    const int tid = threadIdx.x, lane = tid & 63, wid = tid >> 6;
    __shared__ int wred[16];

    // phase 1: prefix = sum cnt[0 .. c*1024)
    int p = 0;
    for (int i = tid; i < c * 1024; i += 1024) p += cnt[i];
    for (int o = 32; o > 0; o >>= 1) p += __shfl_xor(p, o, 64);
    if (lane == 0) wred[wid] = p;
    __syncthreads();
    int prefix = 0;
#pragma unroll
    for (int k = 0; k < 16; ++k) prefix += wred[k];
    __syncthreads();

    // phase 2: local scan of chunk c
    const int i = c * 1024 + tid;
    const int v = (i < N_NODES) ? cnt[i] : 0;
    int x = v;
#pragma unroll
    for (int d = 1; d < 64; d <<= 1) {
        const int t = __shfl_up(x, d, 64);
        if (lane >= d) x += t;
    }
    if (lane == 63) wred[wid] = x;
    __syncthreads();
    int wexc = 0, tot = 0;
#pragma unroll
    for (int k = 0; k < 16; ++k) { if (k < wid) wexc += wred[k]; tot += wred[k]; }
    const int excl = prefix + wexc + x - v;
    if (i < N_NODES) {
        rs[i] = excl; cur[i] = excl;
        if (arr) dis[i] = rsqrtf((float)v + 1.0f);
    }
    if (c == NCHUNK - 1 && tid == 0) rs[N_NODES] = prefix + tot;
}

// ---- merged finish + K1: adjacency scatter || x@W1 MFMA GEMM ----------------
// The scatter (latency-bound, low CU utilization) and the GEMM are mutually
// independent (both only need scan/prep outputs) -- merging overlaps them and
// deletes a launch boundary. Scatter blocks first in the grid: they dispatch
// early; MFMA blocks fill the machine behind them.
__global__ __launch_bounds__(256) void k_finish_mm(
        const int* __restrict__ e_src, const int* __restrict__ e_dst,
        int* __restrict__ curA, int* __restrict__ adjA,
        const int* __restrict__ ps, const int* __restrict__ pd,
        int* __restrict__ curP, int* __restrict__ adjP,
        const float* __restrict__ x, const unsigned short* __restrict__ W1T,
        unsigned short* __restrict__ m1) {
    __shared__ unsigned short sA[32 * 264];   // 16896 B (mm part only)
    const int b = blockIdx.x, tid = threadIdx.x;
    if (b < FA_B) {
        const int e = b * 256 + tid;
        if (e < E2) {
            const int p = atomicAdd(&curA[e_dst[e]], 1);
            adjA[p] = e_src[e];
        }
        return;
    }
    if (b < FMM_SCATTER) {
        const int e = (b - FA_B) * 256 + tid;
        if (e < EP) {
            const int p = atomicAdd(&curP[pd[e]], 1);
            adjP[p] = ps[e];
        }
        return;
    }
    // ---- mm_xW1 part: grid 625x4, 32-row M x 64-col N ----
    const int mb = (b - FMM_SCATTER) >> 2, nb = (b - FMM_SCATTER) & 3;
    const int w = tid >> 6, lane = tid & 63;
    const int l15 = lane & 15, quad = lane >> 4;

    // stage A: 32 rows x 256 k, fp32 -> bf16
    for (int i = tid; i < 2048; i += 256) {
        const int row = i >> 6, kc = (i & 63) << 2;
        const float4 xv = *(const float4*)&x[((long)mb * 32 + row) * 256 + kc];
        union { unsigned short s[4]; unsigned long long ll; } pk;
        pk.s[0] = f2bf(xv.x); pk.s[1] = f2bf(xv.y);
        pk.s[2] = f2bf(xv.z); pk.s[3] = f2bf(xv.w);
        *(unsigned long long*)&sA[row * 264 + kc] = pk.ll;
    }

    bf16x8 breg[8];
#pragma unroll
    for (int ks = 0; ks < 8; ++ks)
        breg[ks] = *(const bf16x8*)&W1T[((nb * 64 + w * 16 + l15) << 8) + ks * 32 + quad * 8];
    __syncthreads();

    f32x4 acc[2];
    acc[0] = (f32x4){0.f,0.f,0.f,0.f};
    acc[1] = (f32x4){0.f,0.f,0.f,0.f};
#pragma unroll
    for (int ks = 0; ks < 8; ++ks) {
#pragma unroll
        for (int st = 0; st < 2; ++st) {
            const bf16x8 af = *(const bf16x8*)&sA[(st * 16 + l15) * 264 + ks * 32 + quad * 8];
            acc[st] = __builtin_amdgcn_mfma_f32_16x16x32_bf16(af, breg[ks], acc[st], 0, 0, 0);
        }
    }
    // D: row = quad*4+r (x-row), col = l15 (n)
#pragma unroll
    for (int st = 0; st < 2; ++st)
#pragma unroll
        for (int r = 0; r < 4; ++r)
            m1[((long)mb * 32 + st * 16 + quad * 4 + r) * 256 + nb * 64 + w * 16 + l15] =
                f2bf(acc[st][r]);
}

// ---- K2: h1bf = bf16(relu(LN(segsum(m1bf[adj]) + b1))); 8-way MLP gather ----
__global__ __launch_bounds__(256) void k_gather_ln(const unsigned short* __restrict__ m1,
                                                   const int* __restrict__ rs,
                                                   const int* __restrict__ adj,
                                                   const float* __restrict__ b1,
                                                   const float* __restrict__ g1,
                                                   const float* __restrict__ bt1,
                                                   unsigned short* __restrict__ h1) {
    const int wid = threadIdx.x >> 6, lane = threadIdx.x & 63;
    const int n = blockIdx.x * 4 + wid;
    const int beg = rs[n], end = rs[n + 1];
    float4 a0 = {0.f,0.f,0.f,0.f}, a1 = {0.f,0.f,0.f,0.f};
    float4 a2 = {0.f,0.f,0.f,0.f}, a3 = {0.f,0.f,0.f,0.f};
    int j = beg;
    for (; j + 7 < end; j += 8) {
        const int s0 = adj[j],     s1 = adj[j + 1], s2 = adj[j + 2], s3 = adj[j + 3];
        const int s4 = adj[j + 4], s5 = adj[j + 5], s6 = adj[j + 6], s7 = adj[j + 7];
        const uint2 u0 = *(const uint2*)(m1 + (long)s0 * 256 + lane * 4);
        const uint2 u1 = *(const uint2*)(m1 + (long)s1 * 256 + lane * 4);
        const uint2 u2 = *(const uint2*)(m1 + (long)s2 * 256 + lane * 4);
        const uint2 u3 = *(const uint2*)(m1 + (long)s3 * 256 + lane * 4);
        const uint2 u4 = *(const uint2*)(m1 + (long)s4 * 256 + lane * 4);
        const uint2 u5 = *(const uint2*)(m1 + (long)s5 * 256 + lane * 4);
        const uint2 u6 = *(const uint2*)(m1 + (long)s6 * 256 + lane * 4);
        const uint2 u7 = *(const uint2*)(m1 + (long)s7 * 256 + lane * 4);
        a0.x += bflo(u0.x); a0.y += bfhi(u0.x); a0.z += bflo(u0.y); a0.w += bfhi(u0.y);
        a1.x += bflo(u1.x); a1.y += bfhi(u1.x); a1.z += bflo(u1.y); a1.w += bfhi(u1.y);
        a2.x += bflo(u2.x); a2.y += bfhi(u2.x); a2.z += bflo(u2.y); a2.w += bfhi(u2.y);
        a3.x += bflo(u3.x); a3.y += bfhi(u3.x); a3.z += bflo(u3.y); a3.w += bfhi(u3.y);
        a0.x += bflo(u4.x); a0.y += bfhi(u4.x); a0.z += bflo(u4.y); a0.w += bfhi(u4.y);
        a1.x += bflo(u5.x); a1.y += bfhi(u5.x); a1.z += bflo(u5.y); a1.w += bfhi(u5.y);
        a2.x += bflo(u6.x); a2.y += bfhi(u6.x); a2.z += bflo(u6.y); a2.w += bfhi(u6.y);
        a3.x += bflo(u7.x); a3.y += bfhi(u7.x); a3.z += bflo(u7.y); a3.w += bfhi(u7.y);
    }
    for (; j + 3 < end; j += 4) {
        const int s0 = adj[j], s1 = adj[j + 1], s2 = adj[j + 2], s3 = adj[j + 3];
        const uint2 u0 = *(const uint2*)(m1 + (long)s0 * 256 + lane * 4);
        const uint2 u1 = *(const uint2*)(m1 + (long)s1 * 256 + lane * 4);
        const uint2 u2 = *(const uint2*)(m1 + (long)s2 * 256 + lane * 4);
        const uint2 u3 = *(const uint2*)(m1 + (long)s3 * 256 + lane * 4);
        a0.x += bflo(u0.x); a0.y += bfhi(u0.x); a0.z += bflo(u0.y); a0.w += bfhi(u0.y);
        a1.x += bflo(u1.x); a1.y += bfhi(u1.x); a1.z += bflo(u1.y); a1.w += bfhi(u1.y);
        a2.x += bflo(u2.x); a2.y += bfhi(u2.x); a2.z += bflo(u2.y); a2.w += bfhi(u2.y);
        a3.x += bflo(u3.x); a3.y += bfhi(u3.x); a3.z += bflo(u3.y); a3.w += bfhi(u3.y);
    }
    for (; j < end; ++j) {
        const int s0 = adj[j];
        const uint2 u = *(const uint2*)(m1 + (long)s0 * 256 + lane * 4);
        a0.x += bflo(u.x); a0.y += bfhi(u.x); a0.z += bflo(u.y); a0.w += bfhi(u.y);
    }
    float4 v;
    const float4 b = *(const float4*)(b1 + lane * 4);
    v.x = (a0.x + a1.x) + (a2.x + a3.x) + b.x;
    v.y = (a0.y + a1.y) + (a2.y + a3.y) + b.y;
    v.z = (a0.z + a1.z) + (a2.z + a3.z) + b.z;
    v.w = (a0.w + a1.w) + (a2.w + a3.w) + b.w;
    float s  = v.x + v.y + v.z + v.w;
    float sq = v.x * v.x + v.y * v.y + v.z * v.z + v.w * v.w;
    for (int o = 32; o > 0; o >>= 1) {
        s  += __shfl_xor(s, o, 64);
        sq += __shfl_xor(sq, o, 64);
    }
    const float mean = s * (1.0f / 256.0f);
    const float var  = sq * (1.0f / 256.0f) - mean * mean;
    const float rsv = rsqrtf(var + 1e-5f);
    const float4 g  = *(const float4*)(g1 + lane * 4);
    const float4 bt = *(const float4*)(bt1 + lane * 4);
    union { unsigned short sh[4]; unsigned long long ll; } pk;
    pk.sh[0] = f2bf(fmaxf((v.x - mean) * rsv * g.x + bt.x, 0.f));
    pk.sh[1] = f2bf(fmaxf((v.y - mean) * rsv * g.y + bt.y, 0.f));
    pk.sh[2] = f2bf(fmaxf((v.z - mean) * rsv * g.z + bt.z, 0.f));
    pk.sh[3] = f2bf(fmaxf((v.w - mean) * rsv * g.w + bt.w, 0.f));
    *(unsigned long long*)&h1[(long)n * 256 + lane * 4] = pk.ll;
}

// ---- K3: hmlbf = bf16(h1bf @ [Wmu|Wlv] interleaved) via MFMA. grid 625x2 ----
__global__ __launch_bounds__(256) void k_mm_hml_mfma(const unsigned short* __restrict__ h1,
                                                     const unsigned short* __restrict__ WmlT,
                                                     unsigned short* __restrict__ hml) {
    __shared__ unsigned short sA[32 * 264];
    const int tid = threadIdx.x;
    const int w = tid >> 6, lane = tid & 63;
    const int l15 = lane & 15, quad = lane >> 4;
    const int mb = blockIdx.x >> 1, nb = blockIdx.x & 1;

    // stage A: 32 rows x 32 chunks of 8 shorts (full 256-k rows)
    for (int i = tid; i < 1024; i += 256) {
        const int row = i >> 5, kc = (i & 31) << 3;
        *(int4*)&sA[row * 264 + kc] = *(const int4*)&h1[((long)mb * 32 + row) * 256 + kc];
    }

    bf16x8 breg[8];
#pragma unroll
    for (int ks = 0; ks < 8; ++ks)
        breg[ks] = *(const bf16x8*)&WmlT[((nb * 64 + w * 16 + l15) << 8) + ks * 32 + quad * 8];
    __syncthreads();

    f32x4 acc[2];
    acc[0] = (f32x4){0.f,0.f,0.f,0.f};
    acc[1] = (f32x4){0.f,0.f,0.f,0.f};
#pragma unroll
    for (int ks = 0; ks < 8; ++ks) {
#pragma unroll
        for (int st = 0; st < 2; ++st) {
            const bf16x8 af = *(const bf16x8*)&sA[(st * 16 + l15) * 264 + ks * 32 + quad * 8];
            acc[st] = __builtin_amdgcn_mfma_f32_16x16x32_bf16(af, breg[ks], acc[st], 0, 0, 0);
        }
    }
#pragma unroll
    for (int st = 0; st < 2; ++st)
#pragma unroll
        for (int r = 0; r < 4; ++r)
            hml[((long)mb * 32 + st * 16 + quad * 4 + r) * 128 + nb * 64 + w * 16 + l15] =
                f2bf(acc[st][r]);
}

// ---- K4: gather hmlbf (interleaved mu/lv) + z (bf16); 8-way MLP gather ----
// kl partial -> per-block array (contended same-address f64 atomics cost ~30us
// in round 4; partial array + k_final is cheaper -- ERRATA round 4).
__global__ __launch_bounds__(256) void k_gather_mulv(const unsigned short* __restrict__ hml,
                                                     const int* __restrict__ rs,
                                                     const int* __restrict__ adj,
                                                     const float* __restrict__ bmu,
                                                     const float* __restrict__ blv,
                                                     const float* __restrict__ eps,
                                                     unsigned short* __restrict__ z,
                                                     double* __restrict__ kl_part) {
    __shared__ double sKL[4];
    const int wid = threadIdx.x >> 6, lane = threadIdx.x & 63;
    const int n = blockIdx.x * 4 + wid;
    const int beg = rs[n], end = rs[n + 1];
    float m0 = 0.f, m1_ = 0.f, m2 = 0.f, m3 = 0.f;
    float l0 = 0.f, l1 = 0.f, l2 = 0.f, l3 = 0.f;
    int j = beg;
    for (; j + 7 < end; j += 8) {
        const int s0 = adj[j],     s1 = adj[j + 1], s2 = adj[j + 2], s3 = adj[j + 3];
        const int s4 = adj[j + 4], s5 = adj[j + 5], s6 = adj[j + 6], s7 = adj[j + 7];
        const unsigned u0 = *(const unsigned*)(hml + (long)s0 * 128 + lane * 2);
        const unsigned u1 = *(const unsigned*)(hml + (long)s1 * 128 + lane * 2);
        const unsigned u2 = *(const unsigned*)(hml + (long)s2 * 128 + lane * 2);
        const unsigned u3 = *(const unsigned*)(hml + (long)s3 * 128 + lane * 2);
        const unsigned u4 = *(const unsigned*)(hml + (long)s4 * 128 + lane * 2);
        const unsigned u5 = *(const unsigned*)(hml + (long)s5 * 128 + lane * 2);
        const unsigned u6 = *(const unsigned*)(hml + (long)s6 * 128 + lane * 2);
        const unsigned u7 = *(const unsigned*)(hml + (long)s7 * 128 + lane * 2);
        m0 += bflo(u0); l0 += bfhi(u0);
        m1_ += bflo(u1); l1 += bfhi(u1);
        m2 += bflo(u2); l2 += bfhi(u2);
        m3 += bflo(u3); l3 += bfhi(u3);
        m0 += bflo(u4); l0 += bfhi(u4);
        m1_ += bflo(u5); l1 += bfhi(u5);
        m2 += bflo(u6); l2 += bfhi(u6);
        m3 += bflo(u7); l3 += bfhi(u7);
    }
    for (; j + 3 < end; j += 4) {
        const int s0 = adj[j], s1 = adj[j + 1], s2 = adj[j + 2], s3 = adj[j + 3];
        const unsigned u0 = *(const unsigned*)(hml + (long)s0 * 128 + lane * 2);
        const unsigned u1 = *(const unsigned*)(hml + (long)s1 * 128 + lane * 2);
        const unsigned u2 = *(const unsigned*)(hml + (long)s2 * 128 + lane * 2);
        const unsigned u3 = *(const unsigned*)(hml + (long)s3 * 128 + lane * 2);
        m0 += bflo(u0); l0 += bfhi(u0);
        m1_ += bflo(u1); l1 += bfhi(u1);
        m2 += bflo(u2); l2 += bfhi(u2);
        m3 += bflo(u3); l3 += bfhi(u3);
    }
    for (; j < end; ++j) {
        const int s0 = adj[j];
        const unsigned u0 = *(const unsigned*)(hml + (long)s0 * 128 + lane * 2);
        m0 += bflo(u0); l0 += bfhi(u0);
    }
    const float mu = (m0 + m1_) + (m2 + m3) + bmu[lane];
    const float lv = (l0 + l1) + (l2 + l3) + blv[lane];
    z[(long)n * 64 + lane] = f2bf(mu + eps[(long)n * 64 + lane] * expf(0.5f * lv));
    float term = 1.0f + lv - mu * mu - expf(lv);
    for (int o = 32; o > 0; o >>= 1) term += __shfl_xor(term, o, 64);
    if (lane == 0) sKL[wid] = (double)term;
    __syncthreads();
    if (threadIdx.x == 0)
        kl_part[blockIdx.x] = sKL[0] + sKL[1] + sKL[2] + sKL[3];
}

// ---- K5/K6: persistent fused decoder layer: gather_norm + 64x64 mm + relu ---
// Grid-stride over 4-node groups: sW (16 KB) staged ONCE per block.
// rows[] is wave-private -> no barrier in the loop.
template <typename IN, typename OUT>
__global__ __launch_bounds__(256) void k_dec_fused(const IN* __restrict__ feat,
                                                   const int* __restrict__ rs,
                                                   const int* __restrict__ adj,
                                                   const float* __restrict__ dis,
                                                   const float* __restrict__ Wd,
                                                   const float* __restrict__ bd,
                                                   OUT* __restrict__ out) {
    __shared__ float sW[64 * 64];
    __shared__ float rows[4][64];
    const int tid = threadIdx.x;
    {
        const float4* w4 = (const float4*)Wd;
        float4* sw4 = (float4*)sW;
        for (int i = tid; i < 1024; i += 256) sw4[i] = w4[i];
    }
    const int wid = tid >> 6, lane = tid & 63;
    const float bdl = bd[lane];
    __syncthreads();

    for (int g = blockIdx.x; g < (N_NODES + 3) / 4; g += DEC_BLOCKS) {
        const int n = g * 4 + wid;
        const int beg = rs[n], end = rs[n + 1];
        float a0 = 0.f, a1 = 0.f, a2 = 0.f, a3 = 0.f;
        int j = beg;
        for (; j + 3 < end; j += 4) {
            const int s0 = adj[j], s1 = adj[j + 1], s2 = adj[j + 2], s3 = adj[j + 3];
            a0 += load_in(&feat[(long)s0 * 64 + lane]) * dis[s0];
            a1 += load_in(&feat[(long)s1 * 64 + lane]) * dis[s1];
            a2 += load_in(&feat[(long)s2 * 64 + lane]) * dis[s2];
            a3 += load_in(&feat[(long)s3 * 64 + lane]) * dis[s3];
        }
        for (; j < end; ++j) {
            const int s0 = adj[j];
            a0 += load_in(&feat[(long)s0 * 64 + lane]) * dis[s0];
        }
        const float dn = dis[n];
        rows[wid][lane] = ((a0 + a1) + (a2 + a3)) * dn
                        + load_in(&feat[(long)n * 64 + lane]) * dn * dn;
        float acc = 0.f;
        for (int k = 0; k < 64; k += 4) {
            const float4 a = *(const float4*)&rows[wid][k];
            acc += a.x * sW[(k+0)*64+lane] + a.y * sW[(k+1)*64+lane]
                 + a.z * sW[(k+2)*64+lane] + a.w * sW[(k+3)*64+lane];
        }
        store_out(fmaxf(acc + bdl, 0.f), &out[(long)n * 64 + lane]);
    }
}

// ---------------- K9: edge MLP, all-register fp16 MFMA, full pipeline --------
// wave = 16 edges x all 64 hidden. B-fragments built entirely in registers:
//   lane (quad,l15): edge = tile*64 + w*16 + l15, owns dims quad*16..quad*16+15
//   frag ks 0/1 -> hu, 2/3 -> hv, 4/5 -> |hu-hv|, 6/7 -> hu*hv (frag-major WaT)
// REGISTER WALL (rounds 2/4/5 ERRATA): any cap <~230 VGPR spills areg. Stay at
// (256,2). 512 blocks = exactly one co-resident pass (2/CU x 256 CU).
// Latency: uv 2-deep nt prefetch; h2 gathers double-buffered; ba/Wb in LDS.
__global__ __launch_bounds__(256, 2) void k_edge_mlp_mfma(
        const __half* __restrict__ h2,
        const int2* __restrict__ uv,
        const unsigned short* __restrict__ WaT,
        const float* __restrict__ ba,
        const float* __restrict__ Wb,
        const float* __restrict__ bb,
        const float* __restrict__ tau,
        double* __restrict__ recon_part) {
    __shared__ float sBa[64], sWb[64];
    __shared__ double sRed[4];
    const int tid = threadIdx.x;
    const int w = tid >> 6, lane = tid & 63;
    const int l15 = lane & 15, quad = lane >> 4;

    if (tid < 64) { sBa[tid] = ba[tid]; sWb[tid] = Wb[tid]; }

    // loop-invariant weight A-fragments (fragment-major layout)
    f16x8 areg[4][8];
#pragma unroll
    for (int nt = 0; nt < 4; ++nt)
#pragma unroll
        for (int ks = 0; ks < 8; ++ks)
            areg[nt][ks] = *(const f16x8*)&WaT[((((nt * 8 + ks) << 6) + lane) << 3)];

    const float bb0 = bb[0];
    const float itau = 1.0f / fmaxf(tau[0], 1e-4f);
    __syncthreads();

    float lsum = 0.f;

    int t = blockIdx.x;
    const int slot = w * 16 + l15;
    // prologue: gathers for tile t; uv one tile ahead
    int2 uvA = ldnt_int2(&uv[t * 64 + slot]);
    int4 hua = *(const int4*)(h2 + (long)uvA.x * 64 + quad * 16);
    int4 hub = *(const int4*)(h2 + (long)uvA.x * 64 + quad * 16 + 8);
    int4 hva = *(const int4*)(h2 + (long)uvA.y * 64 + quad * 16);
    int4 hvb = *(const int4*)(h2 + (long)uvA.y * 64 + quad * 16 + 8);
    int2 uvB = (t + EMLP_BLOCKS < NTILE) ? ldnt_int2(&uv[(t + EMLP_BLOCKS) * 64 + slot]) : uvA;

    for (; t < NTILE; t += EMLP_BLOCKS) {
        // issue uv TWO tiles ahead (nt stream read, full-iteration cover)
        const int t2 = t + 2 * EMLP_BLOCKS;
        const int2 uvC = (t2 < NTILE) ? ldnt_int2(&uv[t2 * 64 + slot]) : uvB;

        // issue NEXT tile's h2 gathers NOW into the dbuf set (uvB landed a
        // full iteration ago) -- whole iteration of cover before consumption
        int4 nhua = hua, nhub = hub, nhva = hva, nhvb = hvb;
        if (t + EMLP_BLOCKS < NTILE) {
            nhua = *(const int4*)(h2 + (long)uvB.x * 64 + quad * 16);
            nhub = *(const int4*)(h2 + (long)uvB.x * 64 + quad * 16 + 8);
            nhva = *(const int4*)(h2 + (long)uvB.y * 64 + quad * 16);
            nhvb = *(const int4*)(h2 + (long)uvB.y * 64 + quad * 16 + 8);
        }

        // derived B-fragments: packed fp16 VALU, register-only
        const f16x8 fad_a = make_ad16(hua, hva);
        const f16x8 fad_b = make_ad16(hub, hvb);
        const f16x8 fpr_a = make_pr16(hua, hva);
        const f16x8 fpr_b = make_pr16(hub, hvb);

        f32x4 acc[4];
#pragma unroll
        for (int nt = 0; nt < 4; ++nt) acc[nt] = (f32x4){0.f, 0.f, 0.f, 0.f};

        const f16x8 bhu_a = *(const f16x8*)&hua;
        const f16x8 bhu_b = *(const f16x8*)&hub;
        const f16x8 bhv_a = *(const f16x8*)&hva;
        const f16x8 bhv_b = *(const f16x8*)&hvb;

#pragma unroll
        for (int nt = 0; nt < 4; ++nt) {
            acc[nt] = __builtin_amdgcn_mfma_f32_16x16x32_f16(areg[nt][0], bhu_a, acc[nt], 0, 0, 0);
            acc[nt] = __builtin_amdgcn_mfma_f32_16x16x32_f16(areg[nt][1], bhu_b, acc[nt], 0, 0, 0);
            acc[nt] = __builtin_amdgcn_mfma_f32_16x16x32_f16(areg[nt][2], bhv_a, acc[nt], 0, 0, 0);
            acc[nt] = __builtin_amdgcn_mfma_f32_16x16x32_f16(areg[nt][3], bhv_b, acc[nt], 0, 0, 0);
            acc[nt] = __builtin_amdgcn_mfma_f32_16x16x32_f16(areg[nt][4], fad_a, acc[nt], 0, 0, 0);
            acc[nt] = __builtin_amdgcn_mfma_f32_16x16x32_f16(areg[nt][5], fad_b, acc[nt], 0, 0, 0);
            acc[nt] = __builtin_amdgcn_mfma_f32_16x16x32_f16(areg[nt][6], fpr_a, acc[nt], 0, 0, 0);
            acc[nt] = __builtin_amdgcn_mfma_f32_16x16x32_f16(areg[nt][7], fpr_b, acc[nt], 0, 0, 0);
        }

        // epilogue: D[n = nt*16 + quad*4 + r][edge = l15]; ba/Wb from LDS
        float s = 0.f;
#pragma unroll
        for (int nt = 0; nt < 4; ++nt) {
            const float4 b4 = *(const float4*)&sBa[nt * 16 + quad * 4];
            const float4 w4 = *(const float4*)&sWb[nt * 16 + quad * 4];
            s += fmaxf(acc[nt][0] + b4.x, 0.f) * w4.x
               + fmaxf(acc[nt][1] + b4.y, 0.f) * w4.y
               + fmaxf(acc[nt][2] + b4.z, 0.f) * w4.z
               + fmaxf(acc[nt][3] + b4.w, 0.f) * w4.w;
        }
        s += __shfl_xor(s, 16, 64);
        s += __shfl_xor(s, 32, 64);
        if (lane < 16) {
            const float logit = (s + bb0) * itau;
            // tiles never mix labels: EP/64 = 1875 exactly (wave-uniform select)
            lsum += (t < POSTILE) ? 5.0f * logsigf(logit) : logsigf(-logit);
        }

        // rotate pipeline registers
        hua = nhua; hub = nhub; hva = nhva; hvb = nhvb;
        uvB = uvC;
    }

    for (int o = 32; o > 0; o >>= 1) lsum += __shfl_xor(lsum, o, 64);
    if (lane == 0) sRed[w] = (double)lsum;
    __syncthreads();
    if (tid == 0)
        recon_part[blockIdx.x] = sRed[0] + sRed[1] + sRed[2] + sRed[3];
}

// ---------------- K10: final reduction over partial arrays ----------------
__global__ __launch_bounds__(1024) void k_final(const double* __restrict__ kl_part,
                                                const double* __restrict__ recon_part,
                                                float* __restrict__ out) {
    __shared__ double sK[16], sR[16];
    const int tid = threadIdx.x, lane = tid & 63, wid = tid >> 6;
    double kl = 0.0, rc = 0.0;
    for (int i = tid; i < 5000; i += 1024) kl += kl_part[i];
    for (int i = tid; i < EMLP_BLOCKS; i += 1024) rc += recon_part[i];
    for (int o = 32; o > 0; o >>= 1) {
        kl += __shfl_xor(kl, o, 64);
        rc += __shfl_xor(rc, o, 64);
    }
    if (lane == 0) { sK[wid] = kl; sR[wid] = rc; }
    __syncthreads();
    if (tid == 0) {
        double K = 0.0, R = 0.0;
        for (int i = 0; i < 16; ++i) { K += sK[i]; R += sR[i]; }
        const double recon = -R / (double)ETOT;
        const double klv = -0.5 * K / ((double)N_NODES * 64.0);
        out[0] = (float)(recon + klv);
        out[1] = (float)recon;
        out[2] = (float)klv;
    }
}

extern "C" void kernel_launch(void* const* d_in, const int* in_sizes, int n_in,
                              void* d_out, int out_size, void* d_ws, size_t ws_size,
                              hipStream_t stream) {
    const float* x   = (const float*)d_in[0];
    const float* eps = (const float*)d_in[1];
    const int* EI    = (const int*)d_in[2];
    const int* pos   = (const int*)d_in[3];
    const int* neg   = (const int*)d_in[4];
    const float* W1  = (const float*)d_in[5];
    const float* b1  = (const float*)d_in[6];
    const float* g1  = (const float*)d_in[7];
    const float* bt1 = (const float*)d_in[8];
    const float* Wmu = (const float*)d_in[9];
    const float* bmu = (const float*)d_in[10];
    const float* Wlv = (const float*)d_in[11];
    const float* blv = (const float*)d_in[12];
    const float* Wd1 = (const float*)d_in[13];
    const float* bd1 = (const float*)d_in[14];
    const float* Wd2 = (const float*)d_in[15];
    const float* bd2 = (const float*)d_in[16];
    const float* Wa  = (const float*)d_in[17];
    const float* ba  = (const float*)d_in[18];
    const float* Wb  = (const float*)d_in[19];
    const float* bb  = (const float*)d_in[20];
    const float* tau = (const float*)d_in[21];

    const int* e_src = EI;
    const int* e_dst = EI + E2;
    const int* ps = pos;
    const int* pd = pos + EP;

    float* ws = (float*)d_ws;
    unsigned short* m1bf  = (unsigned short*)ws;            // [20000,256] bf16 (A)
    unsigned short* hmlbf = (unsigned short*)ws;            // [20000,128] bf16 (A, after m1)
    __half* hdec = (__half*)(ws + 2560000);   // [20000,64] fp16
    __half* h2   = (__half*)(ws + 3840000);   // [20000,64] fp16
    unsigned short* h1bf = (unsigned short*)(ws + 5120000); // [20000,256] bf16 (B)
    unsigned short* z    = (unsigned short*)(ws + 10240000);// [20000,64] bf16
    float* dis   = ws + 11520000;             // [20000]
    unsigned short* WaT = (unsigned short*)(ws + 11540004); // [64,256] fp16 frag-major
    int* cntA = (int*)(ws + 11548200);        // [20000]  (cntP adjacent: 1 memset)
    int* cntP = (int*)(ws + 11568200);        // [20000]
    int* rsA  = (int*)(ws + 11588200);        // [20001]
    int* adjA = (int*)(ws + 11608204);        // [240000]
    int* rsP  = (int*)(ws + 11848204);        // [20001]
    int* adjP = (int*)(ws + 11868208);        // [120000]
    int2* uv  = (int2*)(ws + 11988208);       // [720000] int2 -> ends 13428208
    double* kl_part    = (double*)(ws + 13428208); // [5000]  -> ends 13438208
    double* recon_part = (double*)(ws + 13438208); // [512]
    unsigned short* W1T  = (unsigned short*)(ws + 13440256); // [256,256] bf16
    unsigned short* WmlT = (unsigned short*)(ws + 13473024); // [128,256] bf16
    int* curA = (int*)(ws + 13489408);        // [20000] scan cursors (A)
    int* curP = (int*)(ws + 13509408);        // [20000] scan cursors (P)

    hipMemsetAsync(cntA, 0, 2 * N_NODES * 4, stream);   // cntA+cntP, one call

    // prep + CSR (2 launches: scan, then merged finish||GEMM)
    k_prep_csr<<<WA_B + W1T_B + WML_B + UV_B + HA_B + HP_B, 256, 0, stream>>>(
        Wa, WaT, W1, W1T, Wmu, Wlv, WmlT, pos, neg, uv, e_dst, cntA, pd, cntP);
    k_scan_par<<<2 * NCHUNK, 1024, 0, stream>>>(cntA, rsA, curA, cntP, rsP, curP, dis);
    k_finish_mm<<<FMM_SCATTER + FMM_MM, 256, 0, stream>>>(
        e_src, e_dst, curA, adjA, ps, pd, curP, adjP, x, W1T, m1bf);

    // encoder (MFMA GEMMs + 8-way gathers)
    k_gather_ln<<<5000, 256, 0, stream>>>(m1bf, rsA, adjA, b1, g1, bt1, h1bf);
    k_mm_hml_mfma<<<1250, 256, 0, stream>>>(h1bf, WmlT, hmlbf);
    k_gather_mulv<<<5000, 256, 0, stream>>>(hmlbf, rsA, adjA, bmu, blv, eps, z, kl_part);

    // decoder (persistent grid-stride, fp16 intermediates)
    k_dec_fused<unsigned short, __half><<<DEC_BLOCKS, 256, 0, stream>>>(
        z, rsP, adjP, dis, Wd1, bd1, hdec);
    k_dec_fused<__half, __half><<<DEC_BLOCKS, 256, 0, stream>>>(
        hdec, rsP, adjP, dis, Wd2, bd2, h2);

    // edge MLP + loss
    k_edge_mlp_mfma<<<EMLP_BLOCKS, 256, 0, stream>>>(h2, uv, WaT, ba, Wb, bb, tau, recon_part);
    k_final<<<1, 1024, 0, stream>>>(kl_part, recon_part, (float*)d_out);
}